// Round 7
// baseline (543.592 us; speedup 1.0000x reference)
//
#include <hip/hip_runtime.h>

// Problem constants (fixed by the reference).
constexpr int N = 100000;   // nodes
constexpr int E = 1600000;  // edges
constexpr int D = 128;      // feature dim (both layers)
constexpr int M = 5000;     // mask size

constexpr int SCHUNK = 1024;                       // scan elements per block
constexpr int SBLK = (N + SCHUNK - 1) / SCHUNK;    // 98 scan blocks

constexpr int GEMM_BLKS  = N / 16;                 // 6250 (16 rows/block)
constexpr int BUILD_BLKS = E / 256;                // 6250 (E divisible by 256)

// ---------------- bf16 helpers (RNE pack, cheap unpack) ----------------

__device__ __forceinline__ unsigned int pack_bf16x2(float a, float b) {
    unsigned int ua = __float_as_uint(a);
    unsigned int ub = __float_as_uint(b);
    ua = (ua + 0x7FFFu + ((ua >> 16) & 1u)) >> 16;
    ub = (ub + 0x7FFFu + ((ub >> 16) & 1u)) & 0xFFFF0000u;
    return ua | ub;
}
__device__ __forceinline__ float bf16_lo(unsigned int u) { return __uint_as_float(u << 16); }
__device__ __forceinline__ float bf16_hi(unsigned int u) { return __uint_as_float(u & 0xFFFF0000u); }

// ---------------- GEMM body: 16 rows/block, 256 thr; thread = col-pair x 4 rows ----------------

template <bool BF16IN>
__device__ __forceinline__ void gemm_body(const void* __restrict__ Xin,
                                          const float* __restrict__ W,
                                          unsigned int* __restrict__ Hb, int blk) {
    __shared__ float Xs[16 * D];
    const int t = threadIdx.x;
    const int p = t & 63;    // col pair: cols {2p, 2p+1}
    const int rg = t >> 6;   // row group 0..3
    const int row0 = blk * 16;

    if (BF16IN) {
        const uint4* Xu = (const uint4*)((const unsigned int*)Xin + (size_t)row0 * 64);
        uint4 u = Xu[t];
        float4* Xs4 = (float4*)Xs;
        Xs4[2 * t]     = make_float4(bf16_lo(u.x), bf16_hi(u.x), bf16_lo(u.y), bf16_hi(u.y));
        Xs4[2 * t + 1] = make_float4(bf16_lo(u.z), bf16_hi(u.z), bf16_lo(u.w), bf16_hi(u.w));
    } else {
        const float4* Xf = (const float4*)((const float*)Xin + (size_t)row0 * D);
        float4* Xs4 = (float4*)Xs;
        Xs4[t]       = Xf[t];
        Xs4[t + 256] = Xf[t + 256];
    }
    __syncthreads();

    float acc[4][2] = {};
#pragma unroll 4
    for (int kk = 0; kk < D; kk += 4) {
        float2 w0 = *(const float2*)(W + (kk + 0) * D + 2 * p);
        float2 w1 = *(const float2*)(W + (kk + 1) * D + 2 * p);
        float2 w2 = *(const float2*)(W + (kk + 2) * D + 2 * p);
        float2 w3 = *(const float2*)(W + (kk + 3) * D + 2 * p);
#pragma unroll
        for (int r = 0; r < 4; ++r) {
            float4 xv = *(const float4*)(Xs + (rg * 4 + r) * D + kk);
            acc[r][0] = fmaf(xv.w, w3.x, fmaf(xv.z, w2.x, fmaf(xv.y, w1.x, fmaf(xv.x, w0.x, acc[r][0]))));
            acc[r][1] = fmaf(xv.w, w3.y, fmaf(xv.z, w2.y, fmaf(xv.y, w1.y, fmaf(xv.x, w0.y, acc[r][1]))));
        }
    }
#pragma unroll
    for (int r = 0; r < 4; ++r)
        Hb[(size_t)(row0 + rg * 4 + r) * 64 + p] = pack_bf16x2(acc[r][0], acc[r][1]);
}

// ---------------- fused: GEMM1 + CSR build, INTERLEAVED by block parity ----------------
// packed4[(d<<2)|rep]: bits[47:0] = sum(ew*2^30), bits[63:48] = count (per replica).
// rep = e & 3 spreads atomic contention over 4 addresses per node.

__global__ __launch_bounds__(256) void k_fused1(const float* __restrict__ x,
                                                const float* __restrict__ W1,
                                                unsigned int* __restrict__ A,
                                                const int* __restrict__ dst,
                                                const float* __restrict__ ew,
                                                unsigned long long* __restrict__ packed4,
                                                int* __restrict__ rank) {
    int blk = blockIdx.x >> 1;
    if ((blockIdx.x & 1) == 0) {
        gemm_body<false>(x, W1, A, blk);
    } else {
        int e = blk * 256 + threadIdx.x;  // exact: E = 6250*256
        int d = dst[e];
        unsigned long long val =
            (1ull << 48) | (unsigned long long)(ew[e] * 1073741824.0f + 0.5f);
        unsigned long long old = atomicAdd(&packed4[(d << 2) | (e & 3)], val);
        rank[e] = (int)(old >> 48);
    }
}

__global__ __launch_bounds__(256) void k_gemm2(const unsigned int* __restrict__ B,
                                               const float* __restrict__ W2,
                                               unsigned int* __restrict__ A2) {
    gemm_body<true>(B, W2, A2, blockIdx.x);
}

// ---------------- fused unpack + scan phase 1 ----------------
// Per node: deg/dis from 4 replicas, count, replica prefix offsets; per block: partial sum.

__global__ __launch_bounds__(256) void k_unpack_scan(const unsigned long long* __restrict__ packed4,
                                                     float* __restrict__ dis,
                                                     int* __restrict__ count,
                                                     int* __restrict__ repOff,
                                                     int* __restrict__ blockSums) {
    __shared__ int ws_[4];
    const int t = threadIdx.x;
    const int base = blockIdx.x * SCHUNK + t * 4;  // 4 nodes per thread
    int s = 0;
    int4 cnt = make_int4(0, 0, 0, 0);
    float4 dd = make_float4(0, 0, 0, 0);
#pragma unroll
    for (int r = 0; r < 4; ++r) {
        int node = base + r;
        if (node < N) {
            const unsigned long long* pp = packed4 + ((size_t)node << 2);
            unsigned long long p0 = pp[0], p1 = pp[1], p2 = pp[2], p3 = pp[3];
            int c0 = (int)(p0 >> 48), c1 = (int)(p1 >> 48);
            int c2 = (int)(p2 >> 48), c3 = (int)(p3 >> 48);
            int c = c0 + c1 + c2 + c3;
            double frac = (double)((p0 & 0xFFFFFFFFFFFFull) + (p1 & 0xFFFFFFFFFFFFull) +
                                   (p2 & 0xFFFFFFFFFFFFull) + (p3 & 0xFFFFFFFFFFFFull));
            float deg = 1.0f + (float)(frac * (1.0 / 1073741824.0));
            float di = rsqrtf(deg);
            *(int4*)(repOff + ((size_t)node << 2)) = make_int4(0, c0, c0 + c1, c0 + c1 + c2);
            if (r == 0) { cnt.x = c; dd.x = di; }
            else if (r == 1) { cnt.y = c; dd.y = di; }
            else if (r == 2) { cnt.z = c; dd.z = di; }
            else { cnt.w = c; dd.w = di; }
            s += c;
        }
    }
    if (base + 3 < N) {
        *(int4*)(count + base) = cnt;
        *(float4*)(dis + base) = dd;
    } else {
        if (base + 0 < N) { count[base + 0] = cnt.x; dis[base + 0] = dd.x; }
        if (base + 1 < N) { count[base + 1] = cnt.y; dis[base + 1] = dd.y; }
        if (base + 2 < N) { count[base + 2] = cnt.z; dis[base + 2] = dd.z; }
        if (base + 3 < N) { count[base + 3] = cnt.w; dis[base + 3] = dd.w; }
    }
    for (int off = 32; off > 0; off >>= 1) s += __shfl_down(s, off);
    if ((t & 63) == 0) ws_[t >> 6] = s;
    __syncthreads();
    if (t == 0) blockSums[blockIdx.x] = ws_[0] + ws_[1] + ws_[2] + ws_[3];
}

// ---------------- scan phase 2: exclusive scan of 98 block sums ----------------

__global__ __launch_bounds__(128) void k_scan_blocksums(int* __restrict__ blockSums,
                                                        int* __restrict__ blockOff,
                                                        int* __restrict__ rowStart) {
    __shared__ int sh[128];
    int t = threadIdx.x;
    int v = (t < SBLK) ? blockSums[t] : 0;
    sh[t] = v;
    __syncthreads();
    for (int off = 1; off < 128; off <<= 1) {
        int u = (t >= off) ? sh[t - off] : 0;
        __syncthreads();
        sh[t] += u;
        __syncthreads();
    }
    if (t < SBLK) blockOff[t] = sh[t] - v;  // exclusive
    if (t == 0) rowStart[N] = E;
}

// ---------------- scan phase 3: final exclusive prefixes -> rowStart ----------------

__global__ __launch_bounds__(256) void k_scan_final(const int* __restrict__ count,
                                                    const int* __restrict__ blockOff,
                                                    int* __restrict__ rowStart) {
    __shared__ int waveS[4];
    const int t = threadIdx.x;
    const int lane = t & 63;
    const int wave = t >> 6;
    const int idx = blockIdx.x * SCHUNK + t * 4;

    int4 c = make_int4(0, 0, 0, 0);
    if (idx + 3 < N) c = *(const int4*)(count + idx);
    else {
        if (idx + 0 < N) c.x = count[idx + 0];
        if (idx + 1 < N) c.y = count[idx + 1];
        if (idx + 2 < N) c.z = count[idx + 2];
        if (idx + 3 < N) c.w = count[idx + 3];
    }
    int s = c.x + c.y + c.z + c.w;

    int v = s;
    for (int off = 1; off < 64; off <<= 1) {
        int u = __shfl_up(v, off);
        if (lane >= off) v += u;
    }
    if (lane == 63) waveS[wave] = v;
    __syncthreads();
    int waveBase = 0;
    for (int w = 0; w < 4; ++w) if (w < wave) waveBase += waveS[w];
    int excl = blockOff[blockIdx.x] + waveBase + (v - s);

    int4 rs;
    rs.x = excl;
    rs.y = excl + c.x;
    rs.z = excl + c.x + c.y;
    rs.w = excl + c.x + c.y + c.z;
    if (idx + 3 < N) {
        *(int4*)(rowStart + idx) = rs;
    } else {
        if (idx + 0 < N) rowStart[idx + 0] = rs.x;
        if (idx + 1 < N) rowStart[idx + 1] = rs.y;
        if (idx + 2 < N) rowStart[idx + 2] = rs.z;
        if (idx + 3 < N) rowStart[idx + 3] = rs.w;
    }
}

// ---------------- fill (NO atomics): pairs[rowStart+repOff+rank] = (src, dis[src]*ew) ----------------

__global__ void k_fill(const int* __restrict__ src, const int* __restrict__ dst,
                       const float* __restrict__ ew, const float* __restrict__ dis,
                       const int* __restrict__ rowStart, const int* __restrict__ repOff,
                       const int* __restrict__ rank, int2* __restrict__ pairs) {
    int e = blockIdx.x * 256 + threadIdx.x;
    if (e >= E) return;
    int s = src[e], d = dst[e];
    int pos = rowStart[d] + repOff[(d << 2) | (e & 3)] + rank[e];
    float v = dis[s] * ew[e];
    pairs[pos] = make_int2(s, __float_as_int(v));
}

// ---------------- aggregate layer 1: B = relu(dis*sum + A/deg + b1), bf16 in/out ----------------

__global__ __launch_bounds__(256) void k_aggregate(const unsigned int* __restrict__ Hb,
                                                   const int2* __restrict__ pairs,
                                                   const int* __restrict__ rowStart,
                                                   const float* __restrict__ dis,
                                                   const float* __restrict__ b,
                                                   unsigned int* __restrict__ outB) {
    int node = blockIdx.x * 4 + (threadIdx.x >> 6);
    if (node >= N) return;
    int lane = threadIdx.x & 63;
    int beg = rowStart[node], end = rowStart[node + 1];

    float ax = 0.f, ay = 0.f;
    int j = beg;
    for (; j + 3 < end; j += 4) {  // 4 gathers in flight
        int2 p0 = pairs[j], p1 = pairs[j + 1], p2 = pairs[j + 2], p3 = pairs[j + 3];
        unsigned int h0 = Hb[(size_t)p0.x * 64 + lane];
        unsigned int h1 = Hb[(size_t)p1.x * 64 + lane];
        unsigned int h2 = Hb[(size_t)p2.x * 64 + lane];
        unsigned int h3 = Hb[(size_t)p3.x * 64 + lane];
        float v0 = __int_as_float(p0.y), v1 = __int_as_float(p1.y);
        float v2 = __int_as_float(p2.y), v3 = __int_as_float(p3.y);
        ax += bf16_lo(h0) * v0 + bf16_lo(h1) * v1 + bf16_lo(h2) * v2 + bf16_lo(h3) * v3;
        ay += bf16_hi(h0) * v0 + bf16_hi(h1) * v1 + bf16_hi(h2) * v2 + bf16_hi(h3) * v3;
    }
    for (; j < end; ++j) {
        int2 p0 = pairs[j];
        unsigned int h0 = Hb[(size_t)p0.x * 64 + lane];
        float v0 = __int_as_float(p0.y);
        ax += bf16_lo(h0) * v0;
        ay += bf16_hi(h0) * v0;
    }

    float dd = dis[node];
    float sn = dd * dd;  // self-loop norm = 1/deg
    unsigned int hs = Hb[(size_t)node * 64 + lane];
    float2 bb = ((const float2*)b)[lane];
    float ox = fmaxf(ax * dd + bf16_lo(hs) * sn + bb.x, 0.f);
    float oy = fmaxf(ay * dd + bf16_hi(hs) * sn + bb.y, 0.f);
    outB[(size_t)node * 64 + lane] = pack_bf16x2(ox, oy);
}

// ---------------- layer-2 aggregate at mask nodes only -> d_out ----------------

__global__ __launch_bounds__(256) void k_aggregate_mask(const unsigned int* __restrict__ Hb,
                                                        const int2* __restrict__ pairs,
                                                        const int* __restrict__ rowStart,
                                                        const float* __restrict__ dis,
                                                        const float* __restrict__ b,
                                                        const int* __restrict__ mask,
                                                        const int* __restrict__ y,
                                                        float* __restrict__ out) {
    int i = blockIdx.x * 4 + (threadIdx.x >> 6);
    if (i >= M) return;
    int lane = threadIdx.x & 63;
    int node = mask[i];
    int beg = rowStart[node], end = rowStart[node + 1];

    float ax = 0.f, ay = 0.f;
    int j = beg;
    for (; j + 3 < end; j += 4) {
        int2 p0 = pairs[j], p1 = pairs[j + 1], p2 = pairs[j + 2], p3 = pairs[j + 3];
        unsigned int h0 = Hb[(size_t)p0.x * 64 + lane];
        unsigned int h1 = Hb[(size_t)p1.x * 64 + lane];
        unsigned int h2 = Hb[(size_t)p2.x * 64 + lane];
        unsigned int h3 = Hb[(size_t)p3.x * 64 + lane];
        float v0 = __int_as_float(p0.y), v1 = __int_as_float(p1.y);
        float v2 = __int_as_float(p2.y), v3 = __int_as_float(p3.y);
        ax += bf16_lo(h0) * v0 + bf16_lo(h1) * v1 + bf16_lo(h2) * v2 + bf16_lo(h3) * v3;
        ay += bf16_hi(h0) * v0 + bf16_hi(h1) * v1 + bf16_hi(h2) * v2 + bf16_hi(h3) * v3;
    }
    for (; j < end; ++j) {
        int2 p0 = pairs[j];
        unsigned int h0 = Hb[(size_t)p0.x * 64 + lane];
        float v0 = __int_as_float(p0.y);
        ax += bf16_lo(h0) * v0;
        ay += bf16_hi(h0) * v0;
    }

    float dd = dis[node];
    float sn = dd * dd;
    unsigned int hs = Hb[(size_t)node * 64 + lane];
    float2 bb = ((const float2*)b)[lane];
    float ox = ax * dd + bf16_lo(hs) * sn + bb.x;
    float oy = ay * dd + bf16_hi(hs) * sn + bb.y;
    ((float2*)(out + (size_t)i * D))[lane] = make_float2(ox, oy);
    if (lane == 0) out[(size_t)M * D + i] = (float)y[node];
}

extern "C" void kernel_launch(void* const* d_in, const int* in_sizes, int n_in,
                              void* d_out, int out_size, void* d_ws, size_t ws_size,
                              hipStream_t stream) {
    const float* x  = (const float*)d_in[0];
    const float* ew = (const float*)d_in[1];
    const float* W1 = (const float*)d_in[2];
    const float* b1 = (const float*)d_in[3];
    const float* W2 = (const float*)d_in[4];
    const float* b2 = (const float*)d_in[5];
    const int* eidx = (const int*)d_in[6];
    const int* mask = (const int*)d_in[7];
    const int* y    = (const int*)d_in[8];
    const int* src = eidx;       // edge_index[0]
    const int* dst = eidx + E;   // edge_index[1]

    // Workspace layout (bytes):
    //   packed4   @ 0      : N*4 u64   (3.2 MB)
    //   dis       @ 4 MB   : N f32     (0.4 MB)
    //   count     @ 4.5 MB : N i32     (0.4 MB)
    //   rowStart  @ 5 MB   : N+1 i32   (0.4 MB)
    //   blockSums @ 5.5 MB : SBLK i32
    //   blockOff  @ 5.5M+4K: SBLK i32
    //   repOff    @ 6 MB   : N*4 i32   (1.6 MB)
    //   pairs     @ 8 MB   : E int2    (12.8 MB)
    //   rank      @ 21 MB  : E i32     (6.4 MB)
    //   A  (bf16) @ 28 MB  : N*D bf16  (25.6 MB)
    //   B  (bf16) @ 54 MB  : N*D bf16  (25.6 MB)
    //   A2 (bf16) @ 80 MB  : N*D bf16  (25.6 MB)   total ~105.6 MB
    char* ws = (char*)d_ws;
    unsigned long long* packed4 = (unsigned long long*)(ws);
    float* dis      = (float*)(ws + (size_t)4 * 1024 * 1024);
    int*   count    = (int*)(ws + (size_t)4608 * 1024);
    int*   rowStart = (int*)(ws + (size_t)5120 * 1024);
    int*   blockSums= (int*)(ws + (size_t)5632 * 1024);
    int*   blockOff = (int*)(ws + (size_t)5632 * 1024 + 4096);
    int*   repOff   = (int*)(ws + (size_t)6 * 1024 * 1024);
    int2*  pairs    = (int2*)(ws + (size_t)8 * 1024 * 1024);
    int*   rank     = (int*)(ws + (size_t)21 * 1024 * 1024);
    unsigned int* A  = (unsigned int*)(ws + (size_t)28 * 1024 * 1024);
    unsigned int* B  = (unsigned int*)(ws + (size_t)54 * 1024 * 1024);
    unsigned int* A2 = (unsigned int*)(ws + (size_t)80 * 1024 * 1024);

    // --- fused GEMM1 + CSR build, interleaved by block parity ---
    (void)hipMemsetAsync(packed4, 0, (size_t)N * 4 * sizeof(unsigned long long), stream);
    hipLaunchKernelGGL(k_fused1, dim3(GEMM_BLKS + BUILD_BLKS), dim3(256), 0, stream,
                       x, W1, A, dst, ew, packed4, rank);

    // --- normalization + CSR finalize ---
    hipLaunchKernelGGL(k_unpack_scan, dim3(SBLK), dim3(256), 0, stream,
                       packed4, dis, count, repOff, blockSums);
    hipLaunchKernelGGL(k_scan_blocksums, dim3(1), dim3(128), 0, stream, blockSums, blockOff, rowStart);
    hipLaunchKernelGGL(k_scan_final, dim3(SBLK), dim3(256), 0, stream, count, blockOff, rowStart);
    hipLaunchKernelGGL(k_fill, dim3((E + 255) / 256), dim3(256), 0, stream,
                       src, dst, ew, dis, rowStart, repOff, rank, pairs);

    // --- layer 1 aggregate: B = relu(agg(A) + b1)  [bf16 -> bf16] ---
    hipLaunchKernelGGL(k_aggregate, dim3((N + 3) / 4), dim3(256), 0, stream,
                       A, pairs, rowStart, dis, b1, B);

    // --- layer 2: A2 = B@W2 (bf16) ; out = agg(A2) at mask nodes ---
    hipLaunchKernelGGL(k_gemm2, dim3(GEMM_BLKS), dim3(256), 0, stream, B, W2, A2);
    hipLaunchKernelGGL(k_aggregate_mask, dim3((M + 3) / 4), dim3(256), 0, stream,
                       A2, pairs, rowStart, dis, b2, mask, y, (float*)d_out);
}

// Round 8
// 508.138 us; speedup vs baseline: 1.0698x; 1.0698x over previous
//
#include <hip/hip_runtime.h>

// Problem constants (fixed by the reference).
constexpr int N = 100000;   // nodes
constexpr int E = 1600000;  // edges
constexpr int D = 128;      // feature dim (both layers)
constexpr int M = 5000;     // mask size

constexpr int SCHUNK = 1024;                       // scan elements per block
constexpr int SBLK = (N + SCHUNK - 1) / SCHUNK;    // 98 scan blocks
constexpr int GEMM_BLKS = N / 16;                  // 6250 (16 rows/block)

// ---------------- bf16 helpers (RNE pack, cheap unpack) ----------------

__device__ __forceinline__ unsigned int pack_bf16x2(float a, float b) {
    unsigned int ua = __float_as_uint(a);
    unsigned int ub = __float_as_uint(b);
    ua = (ua + 0x7FFFu + ((ua >> 16) & 1u)) >> 16;
    ub = (ub + 0x7FFFu + ((ub >> 16) & 1u)) & 0xFFFF0000u;
    return ua | ub;
}
__device__ __forceinline__ float bf16_lo(unsigned int u) { return __uint_as_float(u << 16); }
__device__ __forceinline__ float bf16_hi(unsigned int u) { return __uint_as_float(u & 0xFFFF0000u); }

// ---------------- GEMM body: 16 rows/block, 256 thr; thread = col-pair x 4 rows ----------------

template <bool BF16IN>
__device__ __forceinline__ void gemm_body(const void* __restrict__ Xin,
                                          const float* __restrict__ W,
                                          unsigned int* __restrict__ Hb, int blk) {
    __shared__ float Xs[16 * D];
    const int t = threadIdx.x;
    const int p = t & 63;    // col pair: cols {2p, 2p+1}
    const int rg = t >> 6;   // row group 0..3
    const int row0 = blk * 16;

    if (BF16IN) {
        const uint4* Xu = (const uint4*)((const unsigned int*)Xin + (size_t)row0 * 64);
        uint4 u = Xu[t];
        float4* Xs4 = (float4*)Xs;
        Xs4[2 * t]     = make_float4(bf16_lo(u.x), bf16_hi(u.x), bf16_lo(u.y), bf16_hi(u.y));
        Xs4[2 * t + 1] = make_float4(bf16_lo(u.z), bf16_hi(u.z), bf16_lo(u.w), bf16_hi(u.w));
    } else {
        const float4* Xf = (const float4*)((const float*)Xin + (size_t)row0 * D);
        float4* Xs4 = (float4*)Xs;
        Xs4[t]       = Xf[t];
        Xs4[t + 256] = Xf[t + 256];
    }
    __syncthreads();

    float acc[4][2] = {};
#pragma unroll 4
    for (int kk = 0; kk < D; kk += 4) {
        float2 w0 = *(const float2*)(W + (kk + 0) * D + 2 * p);
        float2 w1 = *(const float2*)(W + (kk + 1) * D + 2 * p);
        float2 w2 = *(const float2*)(W + (kk + 2) * D + 2 * p);
        float2 w3 = *(const float2*)(W + (kk + 3) * D + 2 * p);
#pragma unroll
        for (int r = 0; r < 4; ++r) {
            float4 xv = *(const float4*)(Xs + (rg * 4 + r) * D + kk);
            acc[r][0] = fmaf(xv.w, w3.x, fmaf(xv.z, w2.x, fmaf(xv.y, w1.x, fmaf(xv.x, w0.x, acc[r][0]))));
            acc[r][1] = fmaf(xv.w, w3.y, fmaf(xv.z, w2.y, fmaf(xv.y, w1.y, fmaf(xv.x, w0.y, acc[r][1]))));
        }
    }
#pragma unroll
    for (int r = 0; r < 4; ++r)
        Hb[(size_t)(row0 + rg * 4 + r) * 64 + p] = pack_bf16x2(acc[r][0], acc[r][1]);
}

__global__ __launch_bounds__(256) void k_gemm1(const float* __restrict__ x,
                                               const float* __restrict__ W1,
                                               unsigned int* __restrict__ A) {
    gemm_body<false>(x, W1, A, blockIdx.x);
}

__global__ __launch_bounds__(256) void k_gemm2(const unsigned int* __restrict__ B,
                                               const float* __restrict__ W2,
                                               unsigned int* __restrict__ A2) {
    gemm_body<true>(B, W2, A2, blockIdx.x);
}

// ---------------- CSR build: 4 independent u64 atomics per thread (ILP) ----------------
// packed[d]: bits[47:0] = sum(ew*2^30) fixed point, bits[63:48] = count.
// Returned old value's count field = edge's rank within its dst bucket.

constexpr int BEPT = 4;                                  // edges per thread
constexpr int BUILD_BLKS = (E + 256 * BEPT - 1) / (256 * BEPT);  // 1563

__global__ __launch_bounds__(256) void k_build(const int* __restrict__ dst,
                                               const float* __restrict__ ew,
                                               unsigned long long* __restrict__ packed,
                                               int* __restrict__ rank) {
    const int base = blockIdx.x * (256 * BEPT) + threadIdx.x;
    int d[BEPT];
    unsigned long long val[BEPT];
    unsigned long long old[BEPT];
#pragma unroll
    for (int i = 0; i < BEPT; ++i) {
        int e = base + i * 256;
        if (e < E) {
            d[i] = dst[e];
            val[i] = (1ull << 48) | (unsigned long long)(ew[e] * 1073741824.0f + 0.5f);
        }
    }
#pragma unroll
    for (int i = 0; i < BEPT; ++i) {
        int e = base + i * 256;
        if (e < E) old[i] = atomicAdd(&packed[d[i]], val[i]);
    }
#pragma unroll
    for (int i = 0; i < BEPT; ++i) {
        int e = base + i * 256;
        if (e < E) rank[e] = (int)(old[i] >> 48);
    }
}

// ---------------- fused unpack + scan phase 1 ----------------

__global__ __launch_bounds__(256) void k_unpack_scan(const unsigned long long* __restrict__ packed,
                                                     float* __restrict__ dis,
                                                     int* __restrict__ count,
                                                     int* __restrict__ blockSums) {
    __shared__ int ws_[4];
    const int t = threadIdx.x;
    const int base = blockIdx.x * SCHUNK + t * 4;  // 4 nodes per thread
    int s = 0;
    int4 cnt = make_int4(0, 0, 0, 0);
    float4 dd = make_float4(0, 0, 0, 0);
#pragma unroll
    for (int r = 0; r < 4; ++r) {
        int node = base + r;
        if (node < N) {
            unsigned long long p = packed[node];
            int c = (int)(p >> 48);
            float deg = 1.0f + (float)((double)(p & 0xFFFFFFFFFFFFull) * (1.0 / 1073741824.0));
            float di = rsqrtf(deg);
            if (r == 0) { cnt.x = c; dd.x = di; }
            else if (r == 1) { cnt.y = c; dd.y = di; }
            else if (r == 2) { cnt.z = c; dd.z = di; }
            else { cnt.w = c; dd.w = di; }
            s += c;
        }
    }
    if (base + 3 < N) {
        *(int4*)(count + base) = cnt;
        *(float4*)(dis + base) = dd;
    } else {
        if (base + 0 < N) { count[base + 0] = cnt.x; dis[base + 0] = dd.x; }
        if (base + 1 < N) { count[base + 1] = cnt.y; dis[base + 1] = dd.y; }
        if (base + 2 < N) { count[base + 2] = cnt.z; dis[base + 2] = dd.z; }
        if (base + 3 < N) { count[base + 3] = cnt.w; dis[base + 3] = dd.w; }
    }
    for (int off = 32; off > 0; off >>= 1) s += __shfl_down(s, off);
    if ((t & 63) == 0) ws_[t >> 6] = s;
    __syncthreads();
    if (t == 0) blockSums[blockIdx.x] = ws_[0] + ws_[1] + ws_[2] + ws_[3];
}

// ---------------- scan phase 2: exclusive scan of 98 block sums ----------------

__global__ __launch_bounds__(128) void k_scan_blocksums(int* __restrict__ blockSums,
                                                        int* __restrict__ blockOff,
                                                        int* __restrict__ rowStart) {
    __shared__ int sh[128];
    int t = threadIdx.x;
    int v = (t < SBLK) ? blockSums[t] : 0;
    sh[t] = v;
    __syncthreads();
    for (int off = 1; off < 128; off <<= 1) {
        int u = (t >= off) ? sh[t - off] : 0;
        __syncthreads();
        sh[t] += u;
        __syncthreads();
    }
    if (t < SBLK) blockOff[t] = sh[t] - v;  // exclusive
    if (t == 0) rowStart[N] = E;
}

// ---------------- scan phase 3: final exclusive prefixes -> rowStart ----------------

__global__ __launch_bounds__(256) void k_scan_final(const int* __restrict__ count,
                                                    const int* __restrict__ blockOff,
                                                    int* __restrict__ rowStart) {
    __shared__ int waveS[4];
    const int t = threadIdx.x;
    const int lane = t & 63;
    const int wave = t >> 6;
    const int idx = blockIdx.x * SCHUNK + t * 4;

    int4 c = make_int4(0, 0, 0, 0);
    if (idx + 3 < N) c = *(const int4*)(count + idx);
    else {
        if (idx + 0 < N) c.x = count[idx + 0];
        if (idx + 1 < N) c.y = count[idx + 1];
        if (idx + 2 < N) c.z = count[idx + 2];
        if (idx + 3 < N) c.w = count[idx + 3];
    }
    int s = c.x + c.y + c.z + c.w;

    int v = s;
    for (int off = 1; off < 64; off <<= 1) {
        int u = __shfl_up(v, off);
        if (lane >= off) v += u;
    }
    if (lane == 63) waveS[wave] = v;
    __syncthreads();
    int waveBase = 0;
    for (int w = 0; w < 4; ++w) if (w < wave) waveBase += waveS[w];
    int excl = blockOff[blockIdx.x] + waveBase + (v - s);

    int4 rs;
    rs.x = excl;
    rs.y = excl + c.x;
    rs.z = excl + c.x + c.y;
    rs.w = excl + c.x + c.y + c.z;
    if (idx + 3 < N) {
        *(int4*)(rowStart + idx) = rs;
    } else {
        if (idx + 0 < N) rowStart[idx + 0] = rs.x;
        if (idx + 1 < N) rowStart[idx + 1] = rs.y;
        if (idx + 2 < N) rowStart[idx + 2] = rs.z;
        if (idx + 3 < N) rowStart[idx + 3] = rs.w;
    }
}

// ---------------- fill (NO atomics): pairs[rowStart[d]+rank] = (src, dis[src]*ew) ----------------

__global__ void k_fill(const int* __restrict__ src, const int* __restrict__ dst,
                       const float* __restrict__ ew, const float* __restrict__ dis,
                       const int* __restrict__ rowStart, const int* __restrict__ rank,
                       int2* __restrict__ pairs) {
    int e = blockIdx.x * 256 + threadIdx.x;
    if (e >= E) return;
    int s = src[e], d = dst[e];
    int pos = rowStart[d] + rank[e];
    float v = dis[s] * ew[e];
    pairs[pos] = make_int2(s, __float_as_int(v));
}

// ---------------- aggregate layer 1: B = relu(dis*sum + A/deg + b1), bf16 in/out ----------------

__global__ __launch_bounds__(256) void k_aggregate(const unsigned int* __restrict__ Hb,
                                                   const int2* __restrict__ pairs,
                                                   const int* __restrict__ rowStart,
                                                   const float* __restrict__ dis,
                                                   const float* __restrict__ b,
                                                   unsigned int* __restrict__ outB) {
    int node = blockIdx.x * 4 + (threadIdx.x >> 6);
    if (node >= N) return;
    int lane = threadIdx.x & 63;
    int beg = rowStart[node], end = rowStart[node + 1];

    float ax = 0.f, ay = 0.f;
    int j = beg;
    for (; j + 3 < end; j += 4) {  // 4 gathers in flight
        int2 p0 = pairs[j], p1 = pairs[j + 1], p2 = pairs[j + 2], p3 = pairs[j + 3];
        unsigned int h0 = Hb[(size_t)p0.x * 64 + lane];
        unsigned int h1 = Hb[(size_t)p1.x * 64 + lane];
        unsigned int h2 = Hb[(size_t)p2.x * 64 + lane];
        unsigned int h3 = Hb[(size_t)p3.x * 64 + lane];
        float v0 = __int_as_float(p0.y), v1 = __int_as_float(p1.y);
        float v2 = __int_as_float(p2.y), v3 = __int_as_float(p3.y);
        ax += bf16_lo(h0) * v0 + bf16_lo(h1) * v1 + bf16_lo(h2) * v2 + bf16_lo(h3) * v3;
        ay += bf16_hi(h0) * v0 + bf16_hi(h1) * v1 + bf16_hi(h2) * v2 + bf16_hi(h3) * v3;
    }
    for (; j < end; ++j) {
        int2 p0 = pairs[j];
        unsigned int h0 = Hb[(size_t)p0.x * 64 + lane];
        float v0 = __int_as_float(p0.y);
        ax += bf16_lo(h0) * v0;
        ay += bf16_hi(h0) * v0;
    }

    float dd = dis[node];
    float sn = dd * dd;  // self-loop norm = 1/deg
    unsigned int hs = Hb[(size_t)node * 64 + lane];
    float2 bb = ((const float2*)b)[lane];
    float ox = fmaxf(ax * dd + bf16_lo(hs) * sn + bb.x, 0.f);
    float oy = fmaxf(ay * dd + bf16_hi(hs) * sn + bb.y, 0.f);
    outB[(size_t)node * 64 + lane] = pack_bf16x2(ox, oy);
}

// ---------------- layer-2 aggregate at mask nodes only -> d_out ----------------

__global__ __launch_bounds__(256) void k_aggregate_mask(const unsigned int* __restrict__ Hb,
                                                        const int2* __restrict__ pairs,
                                                        const int* __restrict__ rowStart,
                                                        const float* __restrict__ dis,
                                                        const float* __restrict__ b,
                                                        const int* __restrict__ mask,
                                                        const int* __restrict__ y,
                                                        float* __restrict__ out) {
    int i = blockIdx.x * 4 + (threadIdx.x >> 6);
    if (i >= M) return;
    int lane = threadIdx.x & 63;
    int node = mask[i];
    int beg = rowStart[node], end = rowStart[node + 1];

    float ax = 0.f, ay = 0.f;
    int j = beg;
    for (; j + 3 < end; j += 4) {
        int2 p0 = pairs[j], p1 = pairs[j + 1], p2 = pairs[j + 2], p3 = pairs[j + 3];
        unsigned int h0 = Hb[(size_t)p0.x * 64 + lane];
        unsigned int h1 = Hb[(size_t)p1.x * 64 + lane];
        unsigned int h2 = Hb[(size_t)p2.x * 64 + lane];
        unsigned int h3 = Hb[(size_t)p3.x * 64 + lane];
        float v0 = __int_as_float(p0.y), v1 = __int_as_float(p1.y);
        float v2 = __int_as_float(p2.y), v3 = __int_as_float(p3.y);
        ax += bf16_lo(h0) * v0 + bf16_lo(h1) * v1 + bf16_lo(h2) * v2 + bf16_lo(h3) * v3;
        ay += bf16_hi(h0) * v0 + bf16_hi(h1) * v1 + bf16_hi(h2) * v2 + bf16_hi(h3) * v3;
    }
    for (; j < end; ++j) {
        int2 p0 = pairs[j];
        unsigned int h0 = Hb[(size_t)p0.x * 64 + lane];
        float v0 = __int_as_float(p0.y);
        ax += bf16_lo(h0) * v0;
        ay += bf16_hi(h0) * v0;
    }

    float dd = dis[node];
    float sn = dd * dd;
    unsigned int hs = Hb[(size_t)node * 64 + lane];
    float2 bb = ((const float2*)b)[lane];
    float ox = ax * dd + bf16_lo(hs) * sn + bb.x;
    float oy = ay * dd + bf16_hi(hs) * sn + bb.y;
    ((float2*)(out + (size_t)i * D))[lane] = make_float2(ox, oy);
    if (lane == 0) out[(size_t)M * D + i] = (float)y[node];
}

extern "C" void kernel_launch(void* const* d_in, const int* in_sizes, int n_in,
                              void* d_out, int out_size, void* d_ws, size_t ws_size,
                              hipStream_t stream) {
    const float* x  = (const float*)d_in[0];
    const float* ew = (const float*)d_in[1];
    const float* W1 = (const float*)d_in[2];
    const float* b1 = (const float*)d_in[3];
    const float* W2 = (const float*)d_in[4];
    const float* b2 = (const float*)d_in[5];
    const int* eidx = (const int*)d_in[6];
    const int* mask = (const int*)d_in[7];
    const int* y    = (const int*)d_in[8];
    const int* src = eidx;       // edge_index[0]
    const int* dst = eidx + E;   // edge_index[1]

    // Workspace layout (bytes):
    //   packed    @ 0      : N u64     (0.8 MB)
    //   dis       @ 1 MB   : N f32     (0.4 MB)
    //   count     @ 1.5 MB : N i32     (0.4 MB)
    //   rowStart  @ 2 MB   : N+1 i32   (0.4 MB)
    //   blockSums @ 2.5 MB : SBLK i32
    //   blockOff  @ 2.5M+4K: SBLK i32
    //   pairs     @ 3 MB   : E int2    (12.8 MB)
    //   rank      @ 16 MB  : E i32     (6.4 MB)
    //   A  (bf16) @ 24 MB  : N*D bf16  (25.6 MB)
    //   B  (bf16) @ 50 MB  : N*D bf16  (25.6 MB)
    //   A2 (bf16) @ 76 MB  : N*D bf16  (25.6 MB)   total ~101.6 MB
    char* ws = (char*)d_ws;
    unsigned long long* packed = (unsigned long long*)(ws);
    float* dis      = (float*)(ws + (size_t)1024 * 1024);
    int*   count    = (int*)(ws + (size_t)1536 * 1024);
    int*   rowStart = (int*)(ws + (size_t)2048 * 1024);
    int*   blockSums= (int*)(ws + (size_t)2560 * 1024);
    int*   blockOff = (int*)(ws + (size_t)2560 * 1024 + 4096);
    int2*  pairs    = (int2*)(ws + (size_t)3072 * 1024);
    int*   rank     = (int*)(ws + (size_t)16 * 1024 * 1024);
    unsigned int* A  = (unsigned int*)(ws + (size_t)24 * 1024 * 1024);
    unsigned int* B  = (unsigned int*)(ws + (size_t)50 * 1024 * 1024);
    unsigned int* A2 = (unsigned int*)(ws + (size_t)76 * 1024 * 1024);

    // --- CSR build (ILP atomics) + GEMM1, separate kernels ---
    (void)hipMemsetAsync(packed, 0, (size_t)N * sizeof(unsigned long long), stream);
    hipLaunchKernelGGL(k_build, dim3(BUILD_BLKS), dim3(256), 0, stream, dst, ew, packed, rank);
    hipLaunchKernelGGL(k_gemm1, dim3(GEMM_BLKS), dim3(256), 0, stream, x, W1, A);

    // --- normalization + CSR finalize ---
    hipLaunchKernelGGL(k_unpack_scan, dim3(SBLK), dim3(256), 0, stream,
                       packed, dis, count, blockSums);
    hipLaunchKernelGGL(k_scan_blocksums, dim3(1), dim3(128), 0, stream, blockSums, blockOff, rowStart);
    hipLaunchKernelGGL(k_scan_final, dim3(SBLK), dim3(256), 0, stream, count, blockOff, rowStart);
    hipLaunchKernelGGL(k_fill, dim3((E + 255) / 256), dim3(256), 0, stream,
                       src, dst, ew, dis, rowStart, rank, pairs);

    // --- layer 1 aggregate: B = relu(agg(A) + b1)  [bf16 -> bf16] ---
    hipLaunchKernelGGL(k_aggregate, dim3((N + 3) / 4), dim3(256), 0, stream,
                       A, pairs, rowStart, dis, b1, B);

    // --- layer 2: A2 = B@W2 (bf16) ; out = agg(A2) at mask nodes ---
    hipLaunchKernelGGL(k_gemm2, dim3(GEMM_BLKS), dim3(256), 0, stream, B, W2, A2);
    hipLaunchKernelGGL(k_aggregate_mask, dim3((M + 3) / 4), dim3(256), 0, stream,
                       A2, pairs, rowStart, dis, b2, mask, y, (float*)d_out);
}

// Round 9
// 359.354 us; speedup vs baseline: 1.5127x; 1.4140x over previous
//
#include <hip/hip_runtime.h>

// Problem constants (fixed by the reference).
constexpr int N = 100000;   // nodes
constexpr int E = 1600000;  // edges
constexpr int D = 128;      // feature dim (both layers)
constexpr int M = 5000;     // mask size

constexpr int SCHUNK = 1024;                       // scan elements per block
constexpr int SBLK = (N + SCHUNK - 1) / SCHUNK;    // 98 scan blocks
constexpr int MF_BLKS = (N + 255) / 256;           // 391 mfma-gemm blocks (256 rows each)

typedef __attribute__((ext_vector_type(8))) short bf16x8;
typedef __attribute__((ext_vector_type(4))) float f32x4;

// ---------------- bf16 helpers (RNE pack, cheap unpack) ----------------

__device__ __forceinline__ unsigned int pack_bf16x2(float a, float b) {
    unsigned int ua = __float_as_uint(a);
    unsigned int ub = __float_as_uint(b);
    ua = (ua + 0x7FFFu + ((ua >> 16) & 1u)) >> 16;
    ub = (ub + 0x7FFFu + ((ub >> 16) & 1u)) & 0xFFFF0000u;
    return ua | ub;
}
__device__ __forceinline__ unsigned short bf16_rne(float a) {
    unsigned int ua = __float_as_uint(a);
    return (unsigned short)((ua + 0x7FFFu + ((ua >> 16) & 1u)) >> 16);
}
__device__ __forceinline__ float bf16_lo(unsigned int u) { return __uint_as_float(u << 16); }
__device__ __forceinline__ float bf16_hi(unsigned int u) { return __uint_as_float(u & 0xFFFF0000u); }

// ---------------- prep: Wt[n][kk] = pack(W[2kk][n], W[2kk+1][n])  (bf16 W^T) ----------------

__global__ __launch_bounds__(256) void k_prep(const float* __restrict__ W,
                                              unsigned int* __restrict__ Wt) {
    int idx = blockIdx.x * 256 + threadIdx.x;  // uint index, 8192 total
    if (idx >= 128 * 64) return;
    int n = idx >> 6, kk = idx & 63;
    float a = W[(2 * kk) * D + n];
    float b = W[(2 * kk + 1) * D + n];
    Wt[idx] = pack_bf16x2(a, b);
}

// ---------------- MFMA GEMM: 256 rows/block, 4 waves; wave = 64 rows x 128 cols ----------------
// A-frag: A[m=lane&15][k=quad*8+j]; B-frag: B[k=quad*8+j][n=lane&15];
// D: col=lane&15, row=quad*4+reg  (HW-verified layouts, 16x16x32 bf16).
// W^T staged in LDS with 68-uint row stride (bank-conflict padding).

template <bool BF16IN>
__device__ __forceinline__ void gemm_mfma_body(const void* __restrict__ Xin,
                                               const unsigned int* __restrict__ Wt,
                                               unsigned short* __restrict__ out) {
    __shared__ unsigned int Ws[128 * 68];
    const int t = threadIdx.x;
#pragma unroll
    for (int i = 0; i < 8; ++i) {
        int f4 = t + i * 256;        // uint4 index, 2048 total
        int n = f4 >> 4;             // 16 uint4 per n-row
        int k4 = f4 & 15;
        uint4 w = ((const uint4*)Wt)[f4];
        *(uint4*)(&Ws[n * 68 + k4 * 4]) = w;
    }
    __syncthreads();

    const int wv = t >> 6, lane = t & 63;
    const int q = lane >> 4, l15 = lane & 15;
    const int rowBase = blockIdx.x * 256 + wv * 64;

    f32x4 acc[4][8] = {};
#pragma unroll
    for (int kc = 0; kc < 4; ++kc) {
        bf16x8 af[4];
#pragma unroll
        for (int rt = 0; rt < 4; ++rt) {
            int row = rowBase + rt * 16 + l15;
            if (row > N - 1) row = N - 1;   // tail: duplicate last row, stores guarded
            union { uint4 u; bf16x8 v; } cv;
            if (BF16IN) {
                cv.u = *(const uint4*)((const unsigned int*)Xin + (size_t)row * 64 + kc * 16 + q * 4);
            } else {
                const float* xr = (const float*)Xin + (size_t)row * D + kc * 32 + q * 8;
                float4 x0 = *(const float4*)xr;
                float4 x1 = *(const float4*)(xr + 4);
                cv.u.x = pack_bf16x2(x0.x, x0.y);
                cv.u.y = pack_bf16x2(x0.z, x0.w);
                cv.u.z = pack_bf16x2(x1.x, x1.y);
                cv.u.w = pack_bf16x2(x1.z, x1.w);
            }
            af[rt] = cv.v;
        }
#pragma unroll
        for (int ct = 0; ct < 8; ++ct) {
            union { uint4 u; bf16x8 v; } bv;
            bv.u = *(const uint4*)(&Ws[(ct * 16 + l15) * 68 + kc * 16 + q * 4]);
#pragma unroll
            for (int rt = 0; rt < 4; ++rt)
                acc[rt][ct] = __builtin_amdgcn_mfma_f32_16x16x32_bf16(af[rt], bv.v, acc[rt][ct], 0, 0, 0);
        }
    }

#pragma unroll
    for (int rt = 0; rt < 4; ++rt) {
#pragma unroll
        for (int ct = 0; ct < 8; ++ct) {
            int col = ct * 16 + l15;
#pragma unroll
            for (int r = 0; r < 4; ++r) {
                int row = rowBase + rt * 16 + q * 4 + r;
                if (row < N) out[(size_t)row * D + col] = bf16_rne(acc[rt][ct][r]);
            }
        }
    }
}

__global__ __launch_bounds__(256) void k_gemm1(const float* __restrict__ x,
                                               const unsigned int* __restrict__ Wt1,
                                               unsigned short* __restrict__ A) {
    gemm_mfma_body<false>(x, Wt1, A);
}

__global__ __launch_bounds__(256) void k_gemm2(const unsigned short* __restrict__ B,
                                               const unsigned int* __restrict__ Wt2,
                                               unsigned short* __restrict__ A2) {
    gemm_mfma_body<true>(B, Wt2, A2);
}

// ---------------- CSR build: 4 independent u64 atomics per thread (ILP) ----------------
// packed[d]: bits[47:0] = sum(ew*2^30) fixed point, bits[63:48] = count.
// Returned old value's count field = edge's rank within its dst bucket.

constexpr int BEPT = 4;                                  // edges per thread
constexpr int BUILD_BLKS = (E + 256 * BEPT - 1) / (256 * BEPT);  // 1563

__global__ __launch_bounds__(256) void k_build(const int* __restrict__ dst,
                                               const float* __restrict__ ew,
                                               unsigned long long* __restrict__ packed,
                                               int* __restrict__ rank) {
    const int base = blockIdx.x * (256 * BEPT) + threadIdx.x;
    int d[BEPT];
    unsigned long long val[BEPT];
    unsigned long long old[BEPT];
#pragma unroll
    for (int i = 0; i < BEPT; ++i) {
        int e = base + i * 256;
        if (e < E) {
            d[i] = dst[e];
            val[i] = (1ull << 48) | (unsigned long long)(ew[e] * 1073741824.0f + 0.5f);
        }
    }
#pragma unroll
    for (int i = 0; i < BEPT; ++i) {
        int e = base + i * 256;
        if (e < E) old[i] = atomicAdd(&packed[d[i]], val[i]);
    }
#pragma unroll
    for (int i = 0; i < BEPT; ++i) {
        int e = base + i * 256;
        if (e < E) rank[e] = (int)(old[i] >> 48);
    }
}

// ---------------- fused unpack + scan phase 1 ----------------

__global__ __launch_bounds__(256) void k_unpack_scan(const unsigned long long* __restrict__ packed,
                                                     float* __restrict__ dis,
                                                     int* __restrict__ count,
                                                     int* __restrict__ blockSums) {
    __shared__ int ws_[4];
    const int t = threadIdx.x;
    const int base = blockIdx.x * SCHUNK + t * 4;  // 4 nodes per thread
    int s = 0;
    int4 cnt = make_int4(0, 0, 0, 0);
    float4 dd = make_float4(0, 0, 0, 0);
#pragma unroll
    for (int r = 0; r < 4; ++r) {
        int node = base + r;
        if (node < N) {
            unsigned long long p = packed[node];
            int c = (int)(p >> 48);
            float deg = 1.0f + (float)((double)(p & 0xFFFFFFFFFFFFull) * (1.0 / 1073741824.0));
            float di = rsqrtf(deg);
            if (r == 0) { cnt.x = c; dd.x = di; }
            else if (r == 1) { cnt.y = c; dd.y = di; }
            else if (r == 2) { cnt.z = c; dd.z = di; }
            else { cnt.w = c; dd.w = di; }
            s += c;
        }
    }
    if (base + 3 < N) {
        *(int4*)(count + base) = cnt;
        *(float4*)(dis + base) = dd;
    } else {
        if (base + 0 < N) { count[base + 0] = cnt.x; dis[base + 0] = dd.x; }
        if (base + 1 < N) { count[base + 1] = cnt.y; dis[base + 1] = dd.y; }
        if (base + 2 < N) { count[base + 2] = cnt.z; dis[base + 2] = dd.z; }
        if (base + 3 < N) { count[base + 3] = cnt.w; dis[base + 3] = dd.w; }
    }
    for (int off = 32; off > 0; off >>= 1) s += __shfl_down(s, off);
    if ((t & 63) == 0) ws_[t >> 6] = s;
    __syncthreads();
    if (t == 0) blockSums[blockIdx.x] = ws_[0] + ws_[1] + ws_[2] + ws_[3];
}

// ---------------- scan phase 2: exclusive scan of 98 block sums ----------------

__global__ __launch_bounds__(128) void k_scan_blocksums(int* __restrict__ blockSums,
                                                        int* __restrict__ blockOff,
                                                        int* __restrict__ rowStart) {
    __shared__ int sh[128];
    int t = threadIdx.x;
    int v = (t < SBLK) ? blockSums[t] : 0;
    sh[t] = v;
    __syncthreads();
    for (int off = 1; off < 128; off <<= 1) {
        int u = (t >= off) ? sh[t - off] : 0;
        __syncthreads();
        sh[t] += u;
        __syncthreads();
    }
    if (t < SBLK) blockOff[t] = sh[t] - v;  // exclusive
    if (t == 0) rowStart[N] = E;
}

// ---------------- scan phase 3: final exclusive prefixes -> rowStart ----------------

__global__ __launch_bounds__(256) void k_scan_final(const int* __restrict__ count,
                                                    const int* __restrict__ blockOff,
                                                    int* __restrict__ rowStart) {
    __shared__ int waveS[4];
    const int t = threadIdx.x;
    const int lane = t & 63;
    const int wave = t >> 6;
    const int idx = blockIdx.x * SCHUNK + t * 4;

    int4 c = make_int4(0, 0, 0, 0);
    if (idx + 3 < N) c = *(const int4*)(count + idx);
    else {
        if (idx + 0 < N) c.x = count[idx + 0];
        if (idx + 1 < N) c.y = count[idx + 1];
        if (idx + 2 < N) c.z = count[idx + 2];
        if (idx + 3 < N) c.w = count[idx + 3];
    }
    int s = c.x + c.y + c.z + c.w;

    int v = s;
    for (int off = 1; off < 64; off <<= 1) {
        int u = __shfl_up(v, off);
        if (lane >= off) v += u;
    }
    if (lane == 63) waveS[wave] = v;
    __syncthreads();
    int waveBase = 0;
    for (int w = 0; w < 4; ++w) if (w < wave) waveBase += waveS[w];
    int excl = blockOff[blockIdx.x] + waveBase + (v - s);

    int4 rs;
    rs.x = excl;
    rs.y = excl + c.x;
    rs.z = excl + c.x + c.y;
    rs.w = excl + c.x + c.y + c.z;
    if (idx + 3 < N) {
        *(int4*)(rowStart + idx) = rs;
    } else {
        if (idx + 0 < N) rowStart[idx + 0] = rs.x;
        if (idx + 1 < N) rowStart[idx + 1] = rs.y;
        if (idx + 2 < N) rowStart[idx + 2] = rs.z;
        if (idx + 3 < N) rowStart[idx + 3] = rs.w;
    }
}

// ---------------- fill (NO atomics): pairs[rowStart[d]+rank] = (src, dis[src]*ew) ----------------

__global__ void k_fill(const int* __restrict__ src, const int* __restrict__ dst,
                       const float* __restrict__ ew, const float* __restrict__ dis,
                       const int* __restrict__ rowStart, const int* __restrict__ rank,
                       int2* __restrict__ pairs) {
    int e = blockIdx.x * 256 + threadIdx.x;
    if (e >= E) return;
    int s = src[e], d = dst[e];
    int pos = rowStart[d] + rank[e];
    float v = dis[s] * ew[e];
    pairs[pos] = make_int2(s, __float_as_int(v));
}

// ---------------- aggregate layer 1: B = relu(dis*sum + A/deg + b1), bf16 in/out ----------------

__global__ __launch_bounds__(256) void k_aggregate(const unsigned int* __restrict__ Hb,
                                                   const int2* __restrict__ pairs,
                                                   const int* __restrict__ rowStart,
                                                   const float* __restrict__ dis,
                                                   const float* __restrict__ b,
                                                   unsigned int* __restrict__ outB) {
    int node = blockIdx.x * 4 + (threadIdx.x >> 6);
    if (node >= N) return;
    int lane = threadIdx.x & 63;
    int beg = rowStart[node], end = rowStart[node + 1];

    float ax = 0.f, ay = 0.f;
    int j = beg;
    for (; j + 3 < end; j += 4) {  // 4 gathers in flight
        int2 p0 = pairs[j], p1 = pairs[j + 1], p2 = pairs[j + 2], p3 = pairs[j + 3];
        unsigned int h0 = Hb[(size_t)p0.x * 64 + lane];
        unsigned int h1 = Hb[(size_t)p1.x * 64 + lane];
        unsigned int h2 = Hb[(size_t)p2.x * 64 + lane];
        unsigned int h3 = Hb[(size_t)p3.x * 64 + lane];
        float v0 = __int_as_float(p0.y), v1 = __int_as_float(p1.y);
        float v2 = __int_as_float(p2.y), v3 = __int_as_float(p3.y);
        ax += bf16_lo(h0) * v0 + bf16_lo(h1) * v1 + bf16_lo(h2) * v2 + bf16_lo(h3) * v3;
        ay += bf16_hi(h0) * v0 + bf16_hi(h1) * v1 + bf16_hi(h2) * v2 + bf16_hi(h3) * v3;
    }
    for (; j < end; ++j) {
        int2 p0 = pairs[j];
        unsigned int h0 = Hb[(size_t)p0.x * 64 + lane];
        float v0 = __int_as_float(p0.y);
        ax += bf16_lo(h0) * v0;
        ay += bf16_hi(h0) * v0;
    }

    float dd = dis[node];
    float sn = dd * dd;  // self-loop norm = 1/deg
    unsigned int hs = Hb[(size_t)node * 64 + lane];
    float2 bb = ((const float2*)b)[lane];
    float ox = fmaxf(ax * dd + bf16_lo(hs) * sn + bb.x, 0.f);
    float oy = fmaxf(ay * dd + bf16_hi(hs) * sn + bb.y, 0.f);
    outB[(size_t)node * 64 + lane] = pack_bf16x2(ox, oy);
}

// ---------------- layer-2 aggregate at mask nodes only -> d_out ----------------

__global__ __launch_bounds__(256) void k_aggregate_mask(const unsigned int* __restrict__ Hb,
                                                        const int2* __restrict__ pairs,
                                                        const int* __restrict__ rowStart,
                                                        const float* __restrict__ dis,
                                                        const float* __restrict__ b,
                                                        const int* __restrict__ mask,
                                                        const int* __restrict__ y,
                                                        float* __restrict__ out) {
    int i = blockIdx.x * 4 + (threadIdx.x >> 6);
    if (i >= M) return;
    int lane = threadIdx.x & 63;
    int node = mask[i];
    int beg = rowStart[node], end = rowStart[node + 1];

    float ax = 0.f, ay = 0.f;
    int j = beg;
    for (; j + 3 < end; j += 4) {
        int2 p0 = pairs[j], p1 = pairs[j + 1], p2 = pairs[j + 2], p3 = pairs[j + 3];
        unsigned int h0 = Hb[(size_t)p0.x * 64 + lane];
        unsigned int h1 = Hb[(size_t)p1.x * 64 + lane];
        unsigned int h2 = Hb[(size_t)p2.x * 64 + lane];
        unsigned int h3 = Hb[(size_t)p3.x * 64 + lane];
        float v0 = __int_as_float(p0.y), v1 = __int_as_float(p1.y);
        float v2 = __int_as_float(p2.y), v3 = __int_as_float(p3.y);
        ax += bf16_lo(h0) * v0 + bf16_lo(h1) * v1 + bf16_lo(h2) * v2 + bf16_lo(h3) * v3;
        ay += bf16_hi(h0) * v0 + bf16_hi(h1) * v1 + bf16_hi(h2) * v2 + bf16_hi(h3) * v3;
    }
    for (; j < end; ++j) {
        int2 p0 = pairs[j];
        unsigned int h0 = Hb[(size_t)p0.x * 64 + lane];
        float v0 = __int_as_float(p0.y);
        ax += bf16_lo(h0) * v0;
        ay += bf16_hi(h0) * v0;
    }

    float dd = dis[node];
    float sn = dd * dd;
    unsigned int hs = Hb[(size_t)node * 64 + lane];
    float2 bb = ((const float2*)b)[lane];
    float ox = ax * dd + bf16_lo(hs) * sn + bb.x;
    float oy = ay * dd + bf16_hi(hs) * sn + bb.y;
    ((float2*)(out + (size_t)i * D))[lane] = make_float2(ox, oy);
    if (lane == 0) out[(size_t)M * D + i] = (float)y[node];
}

extern "C" void kernel_launch(void* const* d_in, const int* in_sizes, int n_in,
                              void* d_out, int out_size, void* d_ws, size_t ws_size,
                              hipStream_t stream) {
    const float* x  = (const float*)d_in[0];
    const float* ew = (const float*)d_in[1];
    const float* W1 = (const float*)d_in[2];
    const float* b1 = (const float*)d_in[3];
    const float* W2 = (const float*)d_in[4];
    const float* b2 = (const float*)d_in[5];
    const int* eidx = (const int*)d_in[6];
    const int* mask = (const int*)d_in[7];
    const int* y    = (const int*)d_in[8];
    const int* src = eidx;       // edge_index[0]
    const int* dst = eidx + E;   // edge_index[1]

    // Workspace layout (bytes):
    //   packed    @ 0       : N u64     (0.8 MB)
    //   dis       @ 1 MB    : N f32     (0.4 MB)
    //   count     @ 1.5 MB  : N i32     (0.4 MB)
    //   rowStart  @ 2 MB    : N+1 i32   (0.4 MB)
    //   blockSums @ 2.5 MB  : SBLK i32
    //   blockOff  @ 2.5M+4K : SBLK i32
    //   Wt1       @ 2816 KB : 8192 u32  (32 KB)
    //   Wt2       @ 2880 KB : 8192 u32  (32 KB)
    //   pairs     @ 3 MB    : E int2    (12.8 MB)
    //   rank      @ 16 MB   : E i32     (6.4 MB)
    //   A  (bf16) @ 24 MB   : N*D bf16  (25.6 MB)
    //   B  (bf16) @ 50 MB   : N*D bf16  (25.6 MB)
    //   A2 (bf16) @ 76 MB   : N*D bf16  (25.6 MB)   total ~101.6 MB
    char* ws = (char*)d_ws;
    unsigned long long* packed = (unsigned long long*)(ws);
    float* dis      = (float*)(ws + (size_t)1024 * 1024);
    int*   count    = (int*)(ws + (size_t)1536 * 1024);
    int*   rowStart = (int*)(ws + (size_t)2048 * 1024);
    int*   blockSums= (int*)(ws + (size_t)2560 * 1024);
    int*   blockOff = (int*)(ws + (size_t)2560 * 1024 + 4096);
    unsigned int* Wt1 = (unsigned int*)(ws + (size_t)2816 * 1024);
    unsigned int* Wt2 = (unsigned int*)(ws + (size_t)2880 * 1024);
    int2*  pairs    = (int2*)(ws + (size_t)3072 * 1024);
    int*   rank     = (int*)(ws + (size_t)16 * 1024 * 1024);
    unsigned short* A  = (unsigned short*)(ws + (size_t)24 * 1024 * 1024);
    unsigned short* B  = (unsigned short*)(ws + (size_t)50 * 1024 * 1024);
    unsigned short* A2 = (unsigned short*)(ws + (size_t)76 * 1024 * 1024);

    // --- CSR build (ILP atomics) + weight prep + GEMM1 (MFMA) ---
    (void)hipMemsetAsync(packed, 0, (size_t)N * sizeof(unsigned long long), stream);
    hipLaunchKernelGGL(k_build, dim3(BUILD_BLKS), dim3(256), 0, stream, dst, ew, packed, rank);
    hipLaunchKernelGGL(k_prep, dim3(32), dim3(256), 0, stream, W1, Wt1);
    hipLaunchKernelGGL(k_prep, dim3(32), dim3(256), 0, stream, W2, Wt2);
    hipLaunchKernelGGL(k_gemm1, dim3(MF_BLKS), dim3(256), 0, stream, x, Wt1, A);

    // --- normalization + CSR finalize ---
    hipLaunchKernelGGL(k_unpack_scan, dim3(SBLK), dim3(256), 0, stream,
                       packed, dis, count, blockSums);
    hipLaunchKernelGGL(k_scan_blocksums, dim3(1), dim3(128), 0, stream, blockSums, blockOff, rowStart);
    hipLaunchKernelGGL(k_scan_final, dim3(SBLK), dim3(256), 0, stream, count, blockOff, rowStart);
    hipLaunchKernelGGL(k_fill, dim3((E + 255) / 256), dim3(256), 0, stream,
                       src, dst, ew, dis, rowStart, rank, pairs);

    // --- layer 1 aggregate: B = relu(agg(A) + b1)  [bf16 -> bf16] ---
    hipLaunchKernelGGL(k_aggregate, dim3((N + 3) / 4), dim3(256), 0, stream,
                       (const unsigned int*)A, pairs, rowStart, dis, b1, (unsigned int*)B);

    // --- layer 2: A2 = B@W2 (MFMA bf16) ; out = agg(A2) at mask nodes ---
    hipLaunchKernelGGL(k_gemm2, dim3(MF_BLKS), dim3(256), 0, stream, B, Wt2, A2);
    hipLaunchKernelGGL(k_aggregate_mask, dim3((M + 3) / 4), dim3(256), 0, stream,
                       (const unsigned int*)A2, pairs, rowStart, dis, b2, mask, y, (float*)d_out);
}

// Round 10
// 358.750 us; speedup vs baseline: 1.5152x; 1.0017x over previous
//
#include <hip/hip_runtime.h>

// Problem constants (fixed by the reference).
constexpr int N = 100000;   // nodes
constexpr int E = 1600000;  // edges
constexpr int D = 128;      // feature dim (both layers)
constexpr int M = 5000;     // mask size

constexpr int SCHUNK = 1024;                       // scan elements per block
constexpr int SBLK = (N + SCHUNK - 1) / SCHUNK;    // 98 scan blocks
constexpr int MF_BLKS = (N + 255) / 256;           // 391 mfma-gemm blocks (256 rows each)

typedef __attribute__((ext_vector_type(8))) short bf16x8;
typedef __attribute__((ext_vector_type(4))) float f32x4;

// ---------------- bf16 helpers (RNE pack, cheap unpack) ----------------

__device__ __forceinline__ unsigned int pack_bf16x2(float a, float b) {
    unsigned int ua = __float_as_uint(a);
    unsigned int ub = __float_as_uint(b);
    ua = (ua + 0x7FFFu + ((ua >> 16) & 1u)) >> 16;
    ub = (ub + 0x7FFFu + ((ub >> 16) & 1u)) & 0xFFFF0000u;
    return ua | ub;
}
__device__ __forceinline__ unsigned short bf16_rne(float a) {
    unsigned int ua = __float_as_uint(a);
    return (unsigned short)((ua + 0x7FFFu + ((ua >> 16) & 1u)) >> 16);
}
__device__ __forceinline__ float bf16_lo(unsigned int u) { return __uint_as_float(u << 16); }
__device__ __forceinline__ float bf16_hi(unsigned int u) { return __uint_as_float(u & 0xFFFF0000u); }

// ---------------- prep both weights: Wt[n][kk] = pack(W[2kk][n], W[2kk+1][n]) ----------------

__global__ __launch_bounds__(256) void k_prep(const float* __restrict__ W1,
                                              unsigned int* __restrict__ Wt1,
                                              const float* __restrict__ W2,
                                              unsigned int* __restrict__ Wt2) {
    int gi = blockIdx.x * 256 + threadIdx.x;   // 16384 total
    const float* W = (gi < 8192) ? W1 : W2;
    unsigned int* Wt = (gi < 8192) ? Wt1 : Wt2;
    int idx = gi & 8191;
    int n = idx >> 6, kk = idx & 63;
    float a = W[(2 * kk) * D + n];
    float b = W[(2 * kk + 1) * D + n];
    Wt[idx] = pack_bf16x2(a, b);
}

// ---------------- MFMA GEMM: 256 rows/block, 4 waves; wave = 64 rows x 128 cols ----------------
// A-frag: A[m=lane&15][k=quad*8+j]; B-frag: B[k=quad*8+j][n=lane&15];
// D: col=lane&15, row=quad*4+reg  (HW-verified layouts, 16x16x32 bf16).
// W^T staged in LDS with 68-uint row stride (bank-conflict padding).

template <bool BF16IN>
__device__ __forceinline__ void gemm_mfma_body(const void* __restrict__ Xin,
                                               const unsigned int* __restrict__ Wt,
                                               unsigned short* __restrict__ out) {
    __shared__ unsigned int Ws[128 * 68];
    const int t = threadIdx.x;
#pragma unroll
    for (int i = 0; i < 8; ++i) {
        int f4 = t + i * 256;        // uint4 index, 2048 total
        int n = f4 >> 4;             // 16 uint4 per n-row
        int k4 = f4 & 15;
        uint4 w = ((const uint4*)Wt)[f4];
        *(uint4*)(&Ws[n * 68 + k4 * 4]) = w;
    }
    __syncthreads();

    const int wv = t >> 6, lane = t & 63;
    const int q = lane >> 4, l15 = lane & 15;
    const int rowBase = blockIdx.x * 256 + wv * 64;

    f32x4 acc[4][8] = {};
#pragma unroll
    for (int kc = 0; kc < 4; ++kc) {
        bf16x8 af[4];
#pragma unroll
        for (int rt = 0; rt < 4; ++rt) {
            int row = rowBase + rt * 16 + l15;
            if (row > N - 1) row = N - 1;   // tail: duplicate last row, stores guarded
            union { uint4 u; bf16x8 v; } cv;
            if (BF16IN) {
                cv.u = *(const uint4*)((const unsigned int*)Xin + (size_t)row * 64 + kc * 16 + q * 4);
            } else {
                const float* xr = (const float*)Xin + (size_t)row * D + kc * 32 + q * 8;
                float4 x0 = *(const float4*)xr;
                float4 x1 = *(const float4*)(xr + 4);
                cv.u.x = pack_bf16x2(x0.x, x0.y);
                cv.u.y = pack_bf16x2(x0.z, x0.w);
                cv.u.z = pack_bf16x2(x1.x, x1.y);
                cv.u.w = pack_bf16x2(x1.z, x1.w);
            }
            af[rt] = cv.v;
        }
#pragma unroll
        for (int ct = 0; ct < 8; ++ct) {
            union { uint4 u; bf16x8 v; } bv;
            bv.u = *(const uint4*)(&Ws[(ct * 16 + l15) * 68 + kc * 16 + q * 4]);
#pragma unroll
            for (int rt = 0; rt < 4; ++rt)
                acc[rt][ct] = __builtin_amdgcn_mfma_f32_16x16x32_bf16(af[rt], bv.v, acc[rt][ct], 0, 0, 0);
        }
    }

#pragma unroll
    for (int rt = 0; rt < 4; ++rt) {
#pragma unroll
        for (int ct = 0; ct < 8; ++ct) {
            int col = ct * 16 + l15;
#pragma unroll
            for (int r = 0; r < 4; ++r) {
                int row = rowBase + rt * 16 + q * 4 + r;
                if (row < N) out[(size_t)row * D + col] = bf16_rne(acc[rt][ct][r]);
            }
        }
    }
}

__global__ __launch_bounds__(256) void k_gemm1(const float* __restrict__ x,
                                               const unsigned int* __restrict__ Wt1,
                                               unsigned short* __restrict__ A) {
    gemm_mfma_body<false>(x, Wt1, A);
}

__global__ __launch_bounds__(256) void k_gemm2(const unsigned short* __restrict__ B,
                                               const unsigned int* __restrict__ Wt2,
                                               unsigned short* __restrict__ A2) {
    gemm_mfma_body<true>(B, Wt2, A2);
}

// ---------------- CSR build: 4 independent u64 atomics per thread (ILP) ----------------
// packed[d]: bits[47:0] = sum(ew*2^30) fixed point, bits[63:48] = count.
// Returned old value's count field = edge's rank within its dst bucket.

constexpr int BEPT = 4;                                  // edges per thread
constexpr int BUILD_BLKS = (E + 256 * BEPT - 1) / (256 * BEPT);  // 1563

__global__ __launch_bounds__(256) void k_build(const int* __restrict__ dst,
                                               const float* __restrict__ ew,
                                               unsigned long long* __restrict__ packed,
                                               int* __restrict__ rank) {
    const int base = blockIdx.x * (256 * BEPT) + threadIdx.x;
    int d[BEPT];
    unsigned long long val[BEPT];
    unsigned long long old[BEPT];
#pragma unroll
    for (int i = 0; i < BEPT; ++i) {
        int e = base + i * 256;
        if (e < E) {
            d[i] = __builtin_nontemporal_load(dst + e);
            float w = __builtin_nontemporal_load(ew + e);
            val[i] = (1ull << 48) | (unsigned long long)(w * 1073741824.0f + 0.5f);
        }
    }
#pragma unroll
    for (int i = 0; i < BEPT; ++i) {
        int e = base + i * 256;
        if (e < E) old[i] = atomicAdd(&packed[d[i]], val[i]);
    }
#pragma unroll
    for (int i = 0; i < BEPT; ++i) {
        int e = base + i * 256;
        if (e < E) __builtin_nontemporal_store((int)(old[i] >> 48), rank + e);
    }
}

// ---------------- fused unpack + scan phase 1 ----------------

__global__ __launch_bounds__(256) void k_unpack_scan(const unsigned long long* __restrict__ packed,
                                                     float* __restrict__ dis,
                                                     int* __restrict__ count,
                                                     int* __restrict__ blockSums) {
    __shared__ int ws_[4];
    const int t = threadIdx.x;
    const int base = blockIdx.x * SCHUNK + t * 4;  // 4 nodes per thread
    int s = 0;
    int4 cnt = make_int4(0, 0, 0, 0);
    float4 dd = make_float4(0, 0, 0, 0);
#pragma unroll
    for (int r = 0; r < 4; ++r) {
        int node = base + r;
        if (node < N) {
            unsigned long long p = packed[node];
            int c = (int)(p >> 48);
            float deg = 1.0f + (float)((double)(p & 0xFFFFFFFFFFFFull) * (1.0 / 1073741824.0));
            float di = rsqrtf(deg);
            if (r == 0) { cnt.x = c; dd.x = di; }
            else if (r == 1) { cnt.y = c; dd.y = di; }
            else if (r == 2) { cnt.z = c; dd.z = di; }
            else { cnt.w = c; dd.w = di; }
            s += c;
        }
    }
    if (base + 3 < N) {
        *(int4*)(count + base) = cnt;
        *(float4*)(dis + base) = dd;
    } else {
        if (base + 0 < N) { count[base + 0] = cnt.x; dis[base + 0] = dd.x; }
        if (base + 1 < N) { count[base + 1] = cnt.y; dis[base + 1] = dd.y; }
        if (base + 2 < N) { count[base + 2] = cnt.z; dis[base + 2] = dd.z; }
        if (base + 3 < N) { count[base + 3] = cnt.w; dis[base + 3] = dd.w; }
    }
    for (int off = 32; off > 0; off >>= 1) s += __shfl_down(s, off);
    if ((t & 63) == 0) ws_[t >> 6] = s;
    __syncthreads();
    if (t == 0) blockSums[blockIdx.x] = ws_[0] + ws_[1] + ws_[2] + ws_[3];
}

// ---------------- scan final: each block scans the 98 block sums inline, then its chunk ----------------

__global__ __launch_bounds__(256) void k_scan_final(const int* __restrict__ count,
                                                    const int* __restrict__ blockSums,
                                                    int* __restrict__ rowStart) {
    __shared__ int sh[128];
    __shared__ int waveS[4];
    const int t = threadIdx.x;
    const int lane = t & 63;
    const int wave = t >> 6;

    // inline exclusive scan of blockSums (98 entries) -- redundant per block, trivial cost
    if (t < 128) sh[t] = (t < SBLK) ? blockSums[t] : 0;
    __syncthreads();
    for (int off = 1; off < 128; off <<= 1) {
        int u = 0;
        if (t < 128 && t >= off) u = sh[t - off];
        __syncthreads();
        if (t < 128) sh[t] += u;
        __syncthreads();
    }
    const int bOff = sh[blockIdx.x] - blockSums[blockIdx.x];  // exclusive prefix of this block
    if (blockIdx.x == 0 && t == 0) rowStart[N] = E;

    const int idx = blockIdx.x * SCHUNK + t * 4;
    int4 c = make_int4(0, 0, 0, 0);
    if (idx + 3 < N) c = *(const int4*)(count + idx);
    else {
        if (idx + 0 < N) c.x = count[idx + 0];
        if (idx + 1 < N) c.y = count[idx + 1];
        if (idx + 2 < N) c.z = count[idx + 2];
        if (idx + 3 < N) c.w = count[idx + 3];
    }
    int s = c.x + c.y + c.z + c.w;

    int v = s;
    for (int off = 1; off < 64; off <<= 1) {
        int u = __shfl_up(v, off);
        if (lane >= off) v += u;
    }
    if (lane == 63) waveS[wave] = v;
    __syncthreads();
    int waveBase = 0;
    for (int w = 0; w < 4; ++w) if (w < wave) waveBase += waveS[w];
    int excl = bOff + waveBase + (v - s);

    int4 rs;
    rs.x = excl;
    rs.y = excl + c.x;
    rs.z = excl + c.x + c.y;
    rs.w = excl + c.x + c.y + c.z;
    if (idx + 3 < N) {
        *(int4*)(rowStart + idx) = rs;
    } else {
        if (idx + 0 < N) rowStart[idx + 0] = rs.x;
        if (idx + 1 < N) rowStart[idx + 1] = rs.y;
        if (idx + 2 < N) rowStart[idx + 2] = rs.z;
        if (idx + 3 < N) rowStart[idx + 3] = rs.w;
    }
}

// ---------------- fill (NO atomics): pairs[rowStart[d]+rank] = (src, dis[src]*ew) ----------------

__global__ void k_fill(const int* __restrict__ src, const int* __restrict__ dst,
                       const float* __restrict__ ew, const float* __restrict__ dis,
                       const int* __restrict__ rowStart, const int* __restrict__ rank,
                       long long* __restrict__ pairs) {
    int e = blockIdx.x * 256 + threadIdx.x;
    if (e >= E) return;
    int s = __builtin_nontemporal_load(src + e);
    int d = __builtin_nontemporal_load(dst + e);
    float w = __builtin_nontemporal_load(ew + e);
    int rk = __builtin_nontemporal_load(rank + e);
    int pos = rowStart[d] + rk;
    float v = dis[s] * w;
    long long pk = (long long)(((unsigned long long)(unsigned int)__float_as_int(v) << 32) |
                               (unsigned int)s);
    __builtin_nontemporal_store(pk, pairs + pos);
}

// ---------------- aggregate layer 1: B = relu(dis*sum + A/deg + b1), bf16 in/out ----------------
// One wave per node; lane owns a col-pair (uint = 2 bf16). 8 gathers in flight.

__global__ __launch_bounds__(256) void k_aggregate(const unsigned int* __restrict__ Hb,
                                                   const int2* __restrict__ pairs,
                                                   const int* __restrict__ rowStart,
                                                   const float* __restrict__ dis,
                                                   const float* __restrict__ b,
                                                   unsigned int* __restrict__ outB) {
    int node = blockIdx.x * 4 + (threadIdx.x >> 6);
    if (node >= N) return;
    int lane = threadIdx.x & 63;
    int beg = rowStart[node], end = rowStart[node + 1];

    float ax = 0.f, ay = 0.f;
    int j = beg;
    for (; j + 7 < end; j += 8) {  // 8 gathers in flight
        int2 p[8];
        unsigned int h[8];
#pragma unroll
        for (int i = 0; i < 8; ++i) p[i] = pairs[j + i];
#pragma unroll
        for (int i = 0; i < 8; ++i) h[i] = Hb[(size_t)p[i].x * 64 + lane];
#pragma unroll
        for (int i = 0; i < 8; ++i) {
            float v = __int_as_float(p[i].y);
            ax += bf16_lo(h[i]) * v;
            ay += bf16_hi(h[i]) * v;
        }
    }
    for (; j + 3 < end; j += 4) {
        int2 p[4];
        unsigned int h[4];
#pragma unroll
        for (int i = 0; i < 4; ++i) p[i] = pairs[j + i];
#pragma unroll
        for (int i = 0; i < 4; ++i) h[i] = Hb[(size_t)p[i].x * 64 + lane];
#pragma unroll
        for (int i = 0; i < 4; ++i) {
            float v = __int_as_float(p[i].y);
            ax += bf16_lo(h[i]) * v;
            ay += bf16_hi(h[i]) * v;
        }
    }
    for (; j < end; ++j) {
        int2 p0 = pairs[j];
        unsigned int h0 = Hb[(size_t)p0.x * 64 + lane];
        float v0 = __int_as_float(p0.y);
        ax += bf16_lo(h0) * v0;
        ay += bf16_hi(h0) * v0;
    }

    float dd = dis[node];
    float sn = dd * dd;  // self-loop norm = 1/deg
    unsigned int hs = Hb[(size_t)node * 64 + lane];
    float2 bb = ((const float2*)b)[lane];
    float ox = fmaxf(ax * dd + bf16_lo(hs) * sn + bb.x, 0.f);
    float oy = fmaxf(ay * dd + bf16_hi(hs) * sn + bb.y, 0.f);
    __builtin_nontemporal_store(pack_bf16x2(ox, oy), outB + (size_t)node * 64 + lane);
}

// ---------------- layer-2 aggregate at mask nodes only -> d_out ----------------

__global__ __launch_bounds__(256) void k_aggregate_mask(const unsigned int* __restrict__ Hb,
                                                        const int2* __restrict__ pairs,
                                                        const int* __restrict__ rowStart,
                                                        const float* __restrict__ dis,
                                                        const float* __restrict__ b,
                                                        const int* __restrict__ mask,
                                                        const int* __restrict__ y,
                                                        float* __restrict__ out) {
    int i = blockIdx.x * 4 + (threadIdx.x >> 6);
    if (i >= M) return;
    int lane = threadIdx.x & 63;
    int node = mask[i];
    int beg = rowStart[node], end = rowStart[node + 1];

    float ax = 0.f, ay = 0.f;
    int j = beg;
    for (; j + 7 < end; j += 8) {
        int2 p[8];
        unsigned int h[8];
#pragma unroll
        for (int ii = 0; ii < 8; ++ii) p[ii] = pairs[j + ii];
#pragma unroll
        for (int ii = 0; ii < 8; ++ii) h[ii] = Hb[(size_t)p[ii].x * 64 + lane];
#pragma unroll
        for (int ii = 0; ii < 8; ++ii) {
            float v = __int_as_float(p[ii].y);
            ax += bf16_lo(h[ii]) * v;
            ay += bf16_hi(h[ii]) * v;
        }
    }
    for (; j < end; ++j) {
        int2 p0 = pairs[j];
        unsigned int h0 = Hb[(size_t)p0.x * 64 + lane];
        float v0 = __int_as_float(p0.y);
        ax += bf16_lo(h0) * v0;
        ay += bf16_hi(h0) * v0;
    }

    float dd = dis[node];
    float sn = dd * dd;
    unsigned int hs = Hb[(size_t)node * 64 + lane];
    float2 bb = ((const float2*)b)[lane];
    float ox = ax * dd + bf16_lo(hs) * sn + bb.x;
    float oy = ay * dd + bf16_hi(hs) * sn + bb.y;
    ((float2*)(out + (size_t)i * D))[lane] = make_float2(ox, oy);
    if (lane == 0) out[(size_t)M * D + i] = (float)y[node];
}

extern "C" void kernel_launch(void* const* d_in, const int* in_sizes, int n_in,
                              void* d_out, int out_size, void* d_ws, size_t ws_size,
                              hipStream_t stream) {
    const float* x  = (const float*)d_in[0];
    const float* ew = (const float*)d_in[1];
    const float* W1 = (const float*)d_in[2];
    const float* b1 = (const float*)d_in[3];
    const float* W2 = (const float*)d_in[4];
    const float* b2 = (const float*)d_in[5];
    const int* eidx = (const int*)d_in[6];
    const int* mask = (const int*)d_in[7];
    const int* y    = (const int*)d_in[8];
    const int* src = eidx;       // edge_index[0]
    const int* dst = eidx + E;   // edge_index[1]

    // Workspace layout (bytes):
    //   packed    @ 0       : N u64     (0.8 MB)
    //   dis       @ 1 MB    : N f32     (0.4 MB)
    //   count     @ 1.5 MB  : N i32     (0.4 MB)
    //   rowStart  @ 2 MB    : N+1 i32   (0.4 MB)
    //   blockSums @ 2.5 MB  : SBLK i32
    //   Wt1       @ 2816 KB : 8192 u32  (32 KB)
    //   Wt2       @ 2880 KB : 8192 u32  (32 KB)
    //   pairs     @ 3 MB    : E int2    (12.8 MB)
    //   rank      @ 16 MB   : E i32     (6.4 MB)
    //   A  (bf16) @ 24 MB   : N*D bf16  (25.6 MB)
    //   B  (bf16) @ 50 MB   : N*D bf16  (25.6 MB)
    //   A2 (bf16) @ 76 MB   : N*D bf16  (25.6 MB)   total ~101.6 MB
    char* ws = (char*)d_ws;
    unsigned long long* packed = (unsigned long long*)(ws);
    float* dis      = (float*)(ws + (size_t)1024 * 1024);
    int*   count    = (int*)(ws + (size_t)1536 * 1024);
    int*   rowStart = (int*)(ws + (size_t)2048 * 1024);
    int*   blockSums= (int*)(ws + (size_t)2560 * 1024);
    unsigned int* Wt1 = (unsigned int*)(ws + (size_t)2816 * 1024);
    unsigned int* Wt2 = (unsigned int*)(ws + (size_t)2880 * 1024);
    long long* pairs = (long long*)(ws + (size_t)3072 * 1024);
    int*   rank     = (int*)(ws + (size_t)16 * 1024 * 1024);
    unsigned short* A  = (unsigned short*)(ws + (size_t)24 * 1024 * 1024);
    unsigned short* B  = (unsigned short*)(ws + (size_t)50 * 1024 * 1024);
    unsigned short* A2 = (unsigned short*)(ws + (size_t)76 * 1024 * 1024);

    // --- CSR build (ILP atomics) + weight prep + GEMM1 (MFMA) ---
    (void)hipMemsetAsync(packed, 0, (size_t)N * sizeof(unsigned long long), stream);
    hipLaunchKernelGGL(k_build, dim3(BUILD_BLKS), dim3(256), 0, stream, dst, ew, packed, rank);
    hipLaunchKernelGGL(k_prep, dim3(64), dim3(256), 0, stream, W1, Wt1, W2, Wt2);
    hipLaunchKernelGGL(k_gemm1, dim3(MF_BLKS), dim3(256), 0, stream, x, Wt1, A);

    // --- normalization + CSR finalize ---
    hipLaunchKernelGGL(k_unpack_scan, dim3(SBLK), dim3(256), 0, stream,
                       packed, dis, count, blockSums);
    hipLaunchKernelGGL(k_scan_final, dim3(SBLK), dim3(256), 0, stream, count, blockSums, rowStart);
    hipLaunchKernelGGL(k_fill, dim3((E + 255) / 256), dim3(256), 0, stream,
                       src, dst, ew, dis, rowStart, rank, pairs);

    // --- layer 1 aggregate: B = relu(agg(A) + b1)  [bf16 -> bf16] ---
    hipLaunchKernelGGL(k_aggregate, dim3((N + 3) / 4), dim3(256), 0, stream,
                       (const unsigned int*)A, (const int2*)pairs, rowStart, dis, b1,
                       (unsigned int*)B);

    // --- layer 2: A2 = B@W2 (MFMA bf16) ; out = agg(A2) at mask nodes ---
    hipLaunchKernelGGL(k_gemm2, dim3(MF_BLKS), dim3(256), 0, stream, B, Wt2, A2);
    hipLaunchKernelGGL(k_aggregate_mask, dim3((M + 3) / 4), dim3(256), 0, stream,
                       (const unsigned int*)A2, (const int2*)pairs, rowStart, dis, b2, mask, y,
                       (float*)d_out);
}

// Round 11
// 307.110 us; speedup vs baseline: 1.7700x; 1.1681x over previous
//
#include <hip/hip_runtime.h>

// Problem constants (fixed by the reference).
constexpr int N = 100000;   // nodes
constexpr int E = 1600000;  // edges
constexpr int D = 128;      // feature dim (both layers)
constexpr int M = 5000;     // mask size

constexpr int MF_BLKS = (N + 255) / 256;           // 391 mfma-gemm blocks (256 rows each)

// Counting-sort CSR build parameters.
constexpr int NB  = 196;                           // buckets: dst>>9, 512 nodes each
constexpr int EB  = 2048;                          // edges per hist/partition block
constexpr int NPB = (E + EB - 1) / EB;             // 782 partition blocks
constexpr int HL  = NB * NPB;                      // 153272 flat histogram entries
constexpr int SC_BLKS = (HL + 1023) / 1024;        // 150 scan blocks

typedef __attribute__((ext_vector_type(8))) short bf16x8;
typedef __attribute__((ext_vector_type(4))) float f32x4;

// ---------------- bf16 helpers (RNE pack, cheap unpack) ----------------

__device__ __forceinline__ unsigned int pack_bf16x2(float a, float b) {
    unsigned int ua = __float_as_uint(a);
    unsigned int ub = __float_as_uint(b);
    ua = (ua + 0x7FFFu + ((ua >> 16) & 1u)) >> 16;
    ub = (ub + 0x7FFFu + ((ub >> 16) & 1u)) & 0xFFFF0000u;
    return ua | ub;
}
__device__ __forceinline__ unsigned short bf16_rne(float a) {
    unsigned int ua = __float_as_uint(a);
    return (unsigned short)((ua + 0x7FFFu + ((ua >> 16) & 1u)) >> 16);
}
__device__ __forceinline__ float bf16_lo(unsigned int u) { return __uint_as_float(u << 16); }
__device__ __forceinline__ float bf16_hi(unsigned int u) { return __uint_as_float(u & 0xFFFF0000u); }

// ---------------- prep both weights: Wt[n][kk] = pack(W[2kk][n], W[2kk+1][n]) ----------------

__global__ __launch_bounds__(256) void k_prep(const float* __restrict__ W1,
                                              unsigned int* __restrict__ Wt1,
                                              const float* __restrict__ W2,
                                              unsigned int* __restrict__ Wt2) {
    int gi = blockIdx.x * 256 + threadIdx.x;   // 16384 total
    const float* W = (gi < 8192) ? W1 : W2;
    unsigned int* Wt = (gi < 8192) ? Wt1 : Wt2;
    int idx = gi & 8191;
    int n = idx >> 6, kk = idx & 63;
    float a = W[(2 * kk) * D + n];
    float b = W[(2 * kk + 1) * D + n];
    Wt[idx] = pack_bf16x2(a, b);
}

// ---------------- MFMA GEMM: 256 rows/block, 4 waves; wave = 64 rows x 128 cols ----------------
// A-frag: A[m=lane&15][k=quad*8+j]; B-frag: B[k=quad*8+j][n=lane&15];
// D: col=lane&15, row=quad*4+reg  (HW-verified layouts, 16x16x32 bf16).
// W^T staged in LDS with 68-uint row stride (bank-conflict padding).

template <bool BF16IN>
__device__ __forceinline__ void gemm_mfma_body(const void* __restrict__ Xin,
                                               const unsigned int* __restrict__ Wt,
                                               unsigned short* __restrict__ out) {
    __shared__ unsigned int Ws[128 * 68];
    const int t = threadIdx.x;
#pragma unroll
    for (int i = 0; i < 8; ++i) {
        int f4 = t + i * 256;        // uint4 index, 2048 total
        int n = f4 >> 4;             // 16 uint4 per n-row
        int k4 = f4 & 15;
        uint4 w = ((const uint4*)Wt)[f4];
        *(uint4*)(&Ws[n * 68 + k4 * 4]) = w;
    }
    __syncthreads();

    const int wv = t >> 6, lane = t & 63;
    const int q = lane >> 4, l15 = lane & 15;
    const int rowBase = blockIdx.x * 256 + wv * 64;

    f32x4 acc[4][8] = {};
#pragma unroll
    for (int kc = 0; kc < 4; ++kc) {
        bf16x8 af[4];
#pragma unroll
        for (int rt = 0; rt < 4; ++rt) {
            int row = rowBase + rt * 16 + l15;
            if (row > N - 1) row = N - 1;   // tail: duplicate last row, stores guarded
            union { uint4 u; bf16x8 v; } cv;
            if (BF16IN) {
                cv.u = *(const uint4*)((const unsigned int*)Xin + (size_t)row * 64 + kc * 16 + q * 4);
            } else {
                const float* xr = (const float*)Xin + (size_t)row * D + kc * 32 + q * 8;
                float4 x0 = *(const float4*)xr;
                float4 x1 = *(const float4*)(xr + 4);
                cv.u.x = pack_bf16x2(x0.x, x0.y);
                cv.u.y = pack_bf16x2(x0.z, x0.w);
                cv.u.z = pack_bf16x2(x1.x, x1.y);
                cv.u.w = pack_bf16x2(x1.z, x1.w);
            }
            af[rt] = cv.v;
        }
#pragma unroll
        for (int ct = 0; ct < 8; ++ct) {
            union { uint4 u; bf16x8 v; } bv;
            bv.u = *(const uint4*)(&Ws[(ct * 16 + l15) * 68 + kc * 16 + q * 4]);
#pragma unroll
            for (int rt = 0; rt < 4; ++rt)
                acc[rt][ct] = __builtin_amdgcn_mfma_f32_16x16x32_bf16(af[rt], bv.v, acc[rt][ct], 0, 0, 0);
        }
    }

#pragma unroll
    for (int rt = 0; rt < 4; ++rt) {
#pragma unroll
        for (int ct = 0; ct < 8; ++ct) {
            int col = ct * 16 + l15;
#pragma unroll
            for (int r = 0; r < 4; ++r) {
                int row = rowBase + rt * 16 + q * 4 + r;
                if (row < N) out[(size_t)row * D + col] = bf16_rne(acc[rt][ct][r]);
            }
        }
    }
}

__global__ __launch_bounds__(256) void k_gemm1(const float* __restrict__ x,
                                               const unsigned int* __restrict__ Wt1,
                                               unsigned short* __restrict__ A) {
    gemm_mfma_body<false>(x, Wt1, A);
}

__global__ __launch_bounds__(256) void k_gemm2(const unsigned short* __restrict__ B,
                                               const unsigned int* __restrict__ Wt2,
                                               unsigned short* __restrict__ A2) {
    gemm_mfma_body<true>(B, Wt2, A2);
}

// ================= atomic-free CSR build (two-level counting sort) =================

// ---- pass A: per-block bucket histogram (LDS atomics only) ----

__global__ __launch_bounds__(256) void k_hist(const int* __restrict__ dst,
                                              int* __restrict__ hist) {
    __shared__ int h[NB];
    const int t = threadIdx.x;
    if (t < NB) h[t] = 0;
    __syncthreads();
    const int base = blockIdx.x * EB;
#pragma unroll
    for (int i = 0; i < 8; ++i) {
        int e = base + t + i * 256;
        if (e < E) {
            int b = __builtin_nontemporal_load(dst + e) >> 9;
            atomicAdd(&h[b], 1);
        }
    }
    __syncthreads();
    if (t < NB) hist[t * NPB + blockIdx.x] = h[t];
}

// ---- pass B1: per-block partial sums over the HL-long flat histogram ----

__global__ __launch_bounds__(256) void k_scanp(const int* __restrict__ hist,
                                               int* __restrict__ bs) {
    __shared__ int ws_[4];
    const int t = threadIdx.x;
    const int idx = blockIdx.x * 1024 + t * 4;
    int s = 0;
    if (idx + 3 < HL) {
        int4 c = *(const int4*)(hist + idx);
        s = c.x + c.y + c.z + c.w;
    } else {
        for (int i = 0; i < 4; ++i) if (idx + i < HL) s += hist[idx + i];
    }
    for (int off = 32; off > 0; off >>= 1) s += __shfl_down(s, off);
    if ((t & 63) == 0) ws_[t >> 6] = s;
    __syncthreads();
    if (t == 0) bs[blockIdx.x] = ws_[0] + ws_[1] + ws_[2] + ws_[3];
}

// ---- pass B2: final exclusive scan (each block inline-scans the 150 block sums) ----

__global__ __launch_bounds__(256) void k_scanf(const int* __restrict__ hist,
                                               const int* __restrict__ bs,
                                               int* __restrict__ histS) {
    __shared__ int sh[256];
    __shared__ int waveS[4];
    const int t = threadIdx.x;
    const int lane = t & 63;
    const int wave = t >> 6;

    sh[t] = (t < SC_BLKS) ? bs[t] : 0;
    __syncthreads();
    for (int off = 1; off < 256; off <<= 1) {
        int u = (t >= off) ? sh[t - off] : 0;
        __syncthreads();
        sh[t] += u;
        __syncthreads();
    }
    const int bOff = sh[blockIdx.x] - bs[blockIdx.x];

    const int idx = blockIdx.x * 1024 + t * 4;
    int4 c = make_int4(0, 0, 0, 0);
    if (idx + 3 < HL) c = *(const int4*)(hist + idx);
    else {
        if (idx + 0 < HL) c.x = hist[idx + 0];
        if (idx + 1 < HL) c.y = hist[idx + 1];
        if (idx + 2 < HL) c.z = hist[idx + 2];
        if (idx + 3 < HL) c.w = hist[idx + 3];
    }
    int s = c.x + c.y + c.z + c.w;

    int v = s;
    for (int off = 1; off < 64; off <<= 1) {
        int u = __shfl_up(v, off);
        if (lane >= off) v += u;
    }
    if (lane == 63) waveS[wave] = v;
    __syncthreads();
    int waveBase = 0;
    for (int w = 0; w < 4; ++w) if (w < wave) waveBase += waveS[w];
    int excl = bOff + waveBase + (v - s);

    int4 rs;
    rs.x = excl;
    rs.y = excl + c.x;
    rs.z = excl + c.x + c.y;
    rs.w = excl + c.x + c.y + c.z;
    if (idx + 3 < HL) {
        *(int4*)(histS + idx) = rs;
    } else {
        if (idx + 0 < HL) histS[idx + 0] = rs.x;
        if (idx + 1 < HL) histS[idx + 1] = rs.y;
        if (idx + 2 < HL) histS[idx + 2] = rs.z;
        if (idx + 3 < HL) histS[idx + 3] = rs.w;
    }
}

// ---- pass C: partition edges into bucket-contiguous tmp (LDS cursors) ----
// record: bits[8:0]=d&511, bits[28:9]=src, bits[63:32]=ew bits

__global__ __launch_bounds__(256) void k_partition(const int* __restrict__ src,
                                                   const int* __restrict__ dst,
                                                   const float* __restrict__ ew,
                                                   const int* __restrict__ histS,
                                                   unsigned long long* __restrict__ tmp) {
    __shared__ int base_[NB];
    const int t = threadIdx.x;
    if (t < NB) base_[t] = histS[t * NPB + blockIdx.x];
    __syncthreads();
    const int eb = blockIdx.x * EB;
#pragma unroll
    for (int i = 0; i < 8; ++i) {
        int e = eb + t + i * 256;
        if (e < E) {
            int d = __builtin_nontemporal_load(dst + e);
            int s = __builtin_nontemporal_load(src + e);
            float w = __builtin_nontemporal_load(ew + e);
            int b = d >> 9;
            int pos = atomicAdd(&base_[b], 1);
            unsigned long long rec =
                ((unsigned long long)(unsigned int)__float_as_int(w) << 32) |
                ((unsigned int)s << 9) | (unsigned int)(d & 511);
            __builtin_nontemporal_store(rec, tmp + pos);
        }
    }
}

// ---- pass D: per-bucket local sort; writes rowStart, dis, node-sorted pairs ----

__global__ __launch_bounds__(256) void k_local(const unsigned long long* __restrict__ tmp,
                                               const int* __restrict__ histS,
                                               float* __restrict__ dis,
                                               int* __restrict__ rowStart,
                                               int2* __restrict__ pairs) {
    const int b = blockIdx.x;
    const int t = threadIdx.x;
    const int segBeg = histS[b * NPB];
    const int segEnd = (b + 1 < NB) ? histS[(b + 1) * NPB] : E;

    __shared__ int   cnt[512];
    __shared__ float wsum[512];
    __shared__ int   off[512];
    __shared__ int   waveS[4];
    cnt[t] = 0; cnt[t + 256] = 0;
    wsum[t] = 0.f; wsum[t + 256] = 0.f;
    __syncthreads();

    // D1: count + weighted degree per node (LDS atomics)
    for (int e = segBeg + t; e < segEnd; e += 256) {
        unsigned long long rec = tmp[e];
        int dl = (int)(rec & 511);
        float w = __uint_as_float((unsigned int)(rec >> 32));
        atomicAdd(&cnt[dl], 1);
        atomicAdd(&wsum[dl], w);
    }
    __syncthreads();

    // D2: exclusive scan of cnt[512] -> off; emit rowStart + dis
    const int i0 = t * 2, i1 = t * 2 + 1;
    const int c0 = cnt[i0], c1 = cnt[i1];
    const int pv = c0 + c1;
    const int lane = t & 63, wv = t >> 6;
    int v = pv;
    for (int o = 1; o < 64; o <<= 1) {
        int u = __shfl_up(v, o);
        if (lane >= o) v += u;
    }
    if (lane == 63) waveS[wv] = v;
    __syncthreads();
    int wb = 0;
    for (int w = 0; w < 4; ++w) if (w < wv) wb += waveS[w];
    const int ex = wb + v - pv;
    off[i0] = ex;
    off[i1] = ex + c0;
    const int node0 = b * 512 + i0, node1 = b * 512 + i1;
    if (node0 < N) { rowStart[node0] = segBeg + ex;      dis[node0] = rsqrtf(1.0f + wsum[i0]); }
    if (node1 < N) { rowStart[node1] = segBeg + ex + c0; dis[node1] = rsqrtf(1.0f + wsum[i1]); }
    cnt[i0] = 0; cnt[i1] = 0;
    if (b == NB - 1 && t == 0) rowStart[N] = E;
    __syncthreads();

    // D3: scatter into final node-sorted pairs (src, ew-bits)
    for (int e = segBeg + t; e < segEnd; e += 256) {
        unsigned long long rec = tmp[e];
        int dl = (int)(rec & 511);
        int s  = (int)((rec >> 9) & 0xFFFFF);
        unsigned int wbits = (unsigned int)(rec >> 32);
        int r = atomicAdd(&cnt[dl], 1);
        pairs[segBeg + off[dl] + r] = make_int2(s, (int)wbits);
    }
}

// ---- pass E: value fixup: pair.y = ew * dis[src]  (dis is L2-resident) ----

__global__ __launch_bounds__(256) void k_fixup(int2* __restrict__ pairs,
                                               const float* __restrict__ dis) {
    const int base = blockIdx.x * EB + threadIdx.x;
#pragma unroll
    for (int i = 0; i < 8; ++i) {
        int e = base + i * 256;
        if (e < E) {
            int2 p = pairs[e];
            float v = __uint_as_float((unsigned int)p.y) * dis[p.x];
            p.y = __float_as_int(v);
            pairs[e] = p;
        }
    }
}

// ---------------- aggregate layer 1: B = relu(dis*sum + A/deg + b1), bf16 in/out ----------------
// One wave per node; lane owns a col-pair (uint = 2 bf16). 8 gathers in flight.

__global__ __launch_bounds__(256) void k_aggregate(const unsigned int* __restrict__ Hb,
                                                   const int2* __restrict__ pairs,
                                                   const int* __restrict__ rowStart,
                                                   const float* __restrict__ dis,
                                                   const float* __restrict__ b,
                                                   unsigned int* __restrict__ outB) {
    int node = blockIdx.x * 4 + (threadIdx.x >> 6);
    if (node >= N) return;
    int lane = threadIdx.x & 63;
    int beg = rowStart[node], end = rowStart[node + 1];

    float ax = 0.f, ay = 0.f;
    int j = beg;
    for (; j + 7 < end; j += 8) {  // 8 gathers in flight
        int2 p[8];
        unsigned int h[8];
#pragma unroll
        for (int i = 0; i < 8; ++i) p[i] = pairs[j + i];
#pragma unroll
        for (int i = 0; i < 8; ++i) h[i] = Hb[(size_t)p[i].x * 64 + lane];
#pragma unroll
        for (int i = 0; i < 8; ++i) {
            float v = __int_as_float(p[i].y);
            ax += bf16_lo(h[i]) * v;
            ay += bf16_hi(h[i]) * v;
        }
    }
    for (; j + 3 < end; j += 4) {
        int2 p[4];
        unsigned int h[4];
#pragma unroll
        for (int i = 0; i < 4; ++i) p[i] = pairs[j + i];
#pragma unroll
        for (int i = 0; i < 4; ++i) h[i] = Hb[(size_t)p[i].x * 64 + lane];
#pragma unroll
        for (int i = 0; i < 4; ++i) {
            float v = __int_as_float(p[i].y);
            ax += bf16_lo(h[i]) * v;
            ay += bf16_hi(h[i]) * v;
        }
    }
    for (; j < end; ++j) {
        int2 p0 = pairs[j];
        unsigned int h0 = Hb[(size_t)p0.x * 64 + lane];
        float v0 = __int_as_float(p0.y);
        ax += bf16_lo(h0) * v0;
        ay += bf16_hi(h0) * v0;
    }

    float dd = dis[node];
    float sn = dd * dd;  // self-loop norm = 1/deg
    unsigned int hs = Hb[(size_t)node * 64 + lane];
    float2 bb = ((const float2*)b)[lane];
    float ox = fmaxf(ax * dd + bf16_lo(hs) * sn + bb.x, 0.f);
    float oy = fmaxf(ay * dd + bf16_hi(hs) * sn + bb.y, 0.f);
    __builtin_nontemporal_store(pack_bf16x2(ox, oy), outB + (size_t)node * 64 + lane);
}

// ---------------- layer-2 aggregate at mask nodes only -> d_out ----------------

__global__ __launch_bounds__(256) void k_aggregate_mask(const unsigned int* __restrict__ Hb,
                                                        const int2* __restrict__ pairs,
                                                        const int* __restrict__ rowStart,
                                                        const float* __restrict__ dis,
                                                        const float* __restrict__ b,
                                                        const int* __restrict__ mask,
                                                        const int* __restrict__ y,
                                                        float* __restrict__ out) {
    int i = blockIdx.x * 4 + (threadIdx.x >> 6);
    if (i >= M) return;
    int lane = threadIdx.x & 63;
    int node = mask[i];
    int beg = rowStart[node], end = rowStart[node + 1];

    float ax = 0.f, ay = 0.f;
    int j = beg;
    for (; j + 7 < end; j += 8) {
        int2 p[8];
        unsigned int h[8];
#pragma unroll
        for (int ii = 0; ii < 8; ++ii) p[ii] = pairs[j + ii];
#pragma unroll
        for (int ii = 0; ii < 8; ++ii) h[ii] = Hb[(size_t)p[ii].x * 64 + lane];
#pragma unroll
        for (int ii = 0; ii < 8; ++ii) {
            float v = __int_as_float(p[ii].y);
            ax += bf16_lo(h[ii]) * v;
            ay += bf16_hi(h[ii]) * v;
        }
    }
    for (; j < end; ++j) {
        int2 p0 = pairs[j];
        unsigned int h0 = Hb[(size_t)p0.x * 64 + lane];
        float v0 = __int_as_float(p0.y);
        ax += bf16_lo(h0) * v0;
        ay += bf16_hi(h0) * v0;
    }

    float dd = dis[node];
    float sn = dd * dd;
    unsigned int hs = Hb[(size_t)node * 64 + lane];
    float2 bb = ((const float2*)b)[lane];
    float ox = ax * dd + bf16_lo(hs) * sn + bb.x;
    float oy = ay * dd + bf16_hi(hs) * sn + bb.y;
    ((float2*)(out + (size_t)i * D))[lane] = make_float2(ox, oy);
    if (lane == 0) out[(size_t)M * D + i] = (float)y[node];
}

extern "C" void kernel_launch(void* const* d_in, const int* in_sizes, int n_in,
                              void* d_out, int out_size, void* d_ws, size_t ws_size,
                              hipStream_t stream) {
    const float* x  = (const float*)d_in[0];
    const float* ew = (const float*)d_in[1];
    const float* W1 = (const float*)d_in[2];
    const float* b1 = (const float*)d_in[3];
    const float* W2 = (const float*)d_in[4];
    const float* b2 = (const float*)d_in[5];
    const int* eidx = (const int*)d_in[6];
    const int* mask = (const int*)d_in[7];
    const int* y    = (const int*)d_in[8];
    const int* src = eidx;       // edge_index[0]
    const int* dst = eidx + E;   // edge_index[1]

    // Workspace layout (bytes):
    //   dis       @ 0       : N f32       (0.4 MB)
    //   rowStart  @ 512 KB  : N+1 i32     (0.4 MB)
    //   scanBS    @ 1024 KB : SC_BLKS i32 (600 B)
    //   Wt1       @ 1088 KB : 8192 u32    (32 KB)
    //   Wt2       @ 1120 KB : 8192 u32    (32 KB)
    //   hist      @ 1280 KB : HL i32      (613 KB)
    //   histS     @ 1920 KB : HL i32      (613 KB)
    //   pairs     @ 3 MB    : E int2      (12.8 MB)
    //   A  (bf16) @ 16 MB   : N*D bf16    (25.6 MB)  [tmp (E u64, 12.8 MB) aliases A:
    //                                       dead before k_gemm1 writes A]
    //   B  (bf16) @ 42 MB   : N*D bf16    (25.6 MB)
    //   A2 (bf16) @ 68 MB   : N*D bf16    (25.6 MB)   total ~93.6 MB
    char* ws = (char*)d_ws;
    float* dis      = (float*)(ws);
    int*   rowStart = (int*)(ws + (size_t)512 * 1024);
    int*   scanBS   = (int*)(ws + (size_t)1024 * 1024);
    unsigned int* Wt1 = (unsigned int*)(ws + (size_t)1088 * 1024);
    unsigned int* Wt2 = (unsigned int*)(ws + (size_t)1120 * 1024);
    int*   hist     = (int*)(ws + (size_t)1280 * 1024);
    int*   histS    = (int*)(ws + (size_t)1920 * 1024);
    int2*  pairs    = (int2*)(ws + (size_t)3 * 1024 * 1024);
    unsigned short* A  = (unsigned short*)(ws + (size_t)16 * 1024 * 1024);
    unsigned long long* tmp = (unsigned long long*)A;  // aliased; see lifetime note
    unsigned short* B  = (unsigned short*)(ws + (size_t)42 * 1024 * 1024);
    unsigned short* A2 = (unsigned short*)(ws + (size_t)68 * 1024 * 1024);

    // --- atomic-free CSR build (counting sort) ---
    hipLaunchKernelGGL(k_hist, dim3(NPB), dim3(256), 0, stream, dst, hist);
    hipLaunchKernelGGL(k_scanp, dim3(SC_BLKS), dim3(256), 0, stream, hist, scanBS);
    hipLaunchKernelGGL(k_scanf, dim3(SC_BLKS), dim3(256), 0, stream, hist, scanBS, histS);
    hipLaunchKernelGGL(k_partition, dim3(NPB), dim3(256), 0, stream, src, dst, ew, histS, tmp);
    hipLaunchKernelGGL(k_local, dim3(NB), dim3(256), 0, stream, tmp, histS, dis, rowStart, pairs);
    hipLaunchKernelGGL(k_fixup, dim3(NPB), dim3(256), 0, stream, pairs, dis);

    // --- layer 1: A = x@W1 (MFMA) ; B = relu(agg(A) + b1) ---
    hipLaunchKernelGGL(k_prep, dim3(64), dim3(256), 0, stream, W1, Wt1, W2, Wt2);
    hipLaunchKernelGGL(k_gemm1, dim3(MF_BLKS), dim3(256), 0, stream, x, Wt1, A);
    hipLaunchKernelGGL(k_aggregate, dim3((N + 3) / 4), dim3(256), 0, stream,
                       (const unsigned int*)A, pairs, rowStart, dis, b1, (unsigned int*)B);

    // --- layer 2: A2 = B@W2 (MFMA) ; out = agg(A2) at mask nodes ---
    hipLaunchKernelGGL(k_gemm2, dim3(MF_BLKS), dim3(256), 0, stream, B, Wt2, A2);
    hipLaunchKernelGGL(k_aggregate_mask, dim3((M + 3) / 4), dim3(256), 0, stream,
                       (const unsigned int*)A2, pairs, rowStart, dis, b2, mask, y, (float*)d_out);
}

// Round 12
// 292.377 us; speedup vs baseline: 1.8592x; 1.0504x over previous
//
#include <hip/hip_runtime.h>

// Problem constants (fixed by the reference).
constexpr int N = 100000;   // nodes
constexpr int E = 1600000;  // edges
constexpr int D = 128;      // feature dim (both layers)
constexpr int M = 5000;     // mask size

constexpr int MF_BLKS = (N + 255) / 256;           // 391 mfma-gemm blocks (256 rows each)

// Counting-sort CSR build parameters.
constexpr int NB  = 196;                           // buckets: dst>>9, 512 nodes each
constexpr int EB  = 2048;                          // edges per hist/partition block
constexpr int NPB = (E + EB - 1) / EB;             // 782 partition blocks
constexpr int HL  = NB * NPB;                      // 153272 flat histogram entries
constexpr int SC_BLKS = (HL + 1023) / 1024;        // 150 scan blocks
constexpr int PREP_BLKS = 64;                      // weight-prep blocks (16384 threads)
constexpr int MB_BLKS = (M + 255) / 256;           // 20 maskbit blocks

typedef __attribute__((ext_vector_type(8))) short bf16x8;
typedef __attribute__((ext_vector_type(4))) float f32x4;

// ---------------- bf16 helpers (RNE pack, cheap unpack) ----------------

__device__ __forceinline__ unsigned int pack_bf16x2(float a, float b) {
    unsigned int ua = __float_as_uint(a);
    unsigned int ub = __float_as_uint(b);
    ua = (ua + 0x7FFFu + ((ua >> 16) & 1u)) >> 16;
    ub = (ub + 0x7FFFu + ((ub >> 16) & 1u)) & 0xFFFF0000u;
    return ua | ub;
}
__device__ __forceinline__ unsigned short bf16_rne(float a) {
    unsigned int ua = __float_as_uint(a);
    return (unsigned short)((ua + 0x7FFFu + ((ua >> 16) & 1u)) >> 16);
}
__device__ __forceinline__ float bf16_lo(unsigned int u) { return __uint_as_float(u << 16); }
__device__ __forceinline__ float bf16_hi(unsigned int u) { return __uint_as_float(u & 0xFFFF0000u); }

// ---------------- misc1: hist (LDS atomics) + weight prep + maskbit ----------------

__global__ __launch_bounds__(256) void k_misc1(const int* __restrict__ dst,
                                               int* __restrict__ hist,
                                               const float* __restrict__ W1,
                                               unsigned int* __restrict__ Wt1,
                                               const float* __restrict__ W2,
                                               unsigned int* __restrict__ Wt2,
                                               const int* __restrict__ mask,
                                               unsigned int* __restrict__ maskbit,
                                               unsigned int* __restrict__ needed) {
    __shared__ int h[NB];
    const int t = threadIdx.x;
    if (blockIdx.x < NPB) {
        if (t < NB) h[t] = 0;
        __syncthreads();
        const int base = blockIdx.x * EB;
#pragma unroll
        for (int i = 0; i < 8; ++i) {
            int e = base + t + i * 256;
            if (e < E) {
                int b = __builtin_nontemporal_load(dst + e) >> 9;
                atomicAdd(&h[b], 1);
            }
        }
        __syncthreads();
        if (t < NB) hist[t * NPB + blockIdx.x] = h[t];
    } else if (blockIdx.x < NPB + PREP_BLKS) {
        int gi = (blockIdx.x - NPB) * 256 + t;   // 16384 total
        const float* W = (gi < 8192) ? W1 : W2;
        unsigned int* Wt = (gi < 8192) ? Wt1 : Wt2;
        int idx = gi & 8191;
        int n = idx >> 6, kk = idx & 63;
        float a = W[(2 * kk) * D + n];
        float b = W[(2 * kk + 1) * D + n];
        Wt[idx] = pack_bf16x2(a, b);
    } else {
        int i = (blockIdx.x - NPB - PREP_BLKS) * 256 + t;
        if (i < M) {
            int n = mask[i];
            atomicOr(&maskbit[n >> 5], 1u << (n & 31));
            atomicOr(&needed[n >> 5], 1u << (n & 31));  // masked nodes need their own row
        }
    }
}

// ---------------- misc2: scan partials + needed-set edge scan ----------------

__global__ __launch_bounds__(256) void k_misc2(const int* __restrict__ hist,
                                               int* __restrict__ bs,
                                               const unsigned int* __restrict__ maskbit,
                                               const int* __restrict__ src,
                                               const int* __restrict__ dst,
                                               unsigned int* __restrict__ needed) {
    __shared__ int ws_[4];
    const int t = threadIdx.x;
    if (blockIdx.x < SC_BLKS) {
        const int idx = blockIdx.x * 1024 + t * 4;
        int s = 0;
        if (idx + 3 < HL) {
            int4 c = *(const int4*)(hist + idx);
            s = c.x + c.y + c.z + c.w;
        } else {
            for (int i = 0; i < 4; ++i) if (idx + i < HL) s += hist[idx + i];
        }
        for (int off = 32; off > 0; off >>= 1) s += __shfl_down(s, off);
        if ((t & 63) == 0) ws_[t >> 6] = s;
        __syncthreads();
        if (t == 0) bs[blockIdx.x] = ws_[0] + ws_[1] + ws_[2] + ws_[3];
    } else {
        const int base = (blockIdx.x - SC_BLKS) * EB;
#pragma unroll
        for (int i = 0; i < 8; ++i) {
            int e = base + t + i * 256;
            if (e < E) {
                int d = __builtin_nontemporal_load(dst + e);
                if ((maskbit[d >> 5] >> (d & 31)) & 1u) {
                    int s = src[e];
                    atomicOr(&needed[s >> 5], 1u << (s & 31));
                }
            }
        }
    }
}

// ---- scan final: each block inline-scans the 150 block sums, then its chunk ----

__global__ __launch_bounds__(256) void k_scanf(const int* __restrict__ hist,
                                               const int* __restrict__ bs,
                                               int* __restrict__ histS) {
    __shared__ int sh[256];
    __shared__ int waveS[4];
    const int t = threadIdx.x;
    const int lane = t & 63;
    const int wave = t >> 6;

    sh[t] = (t < SC_BLKS) ? bs[t] : 0;
    __syncthreads();
    for (int off = 1; off < 256; off <<= 1) {
        int u = (t >= off) ? sh[t - off] : 0;
        __syncthreads();
        sh[t] += u;
        __syncthreads();
    }
    const int bOff = sh[blockIdx.x] - bs[blockIdx.x];

    const int idx = blockIdx.x * 1024 + t * 4;
    int4 c = make_int4(0, 0, 0, 0);
    if (idx + 3 < HL) c = *(const int4*)(hist + idx);
    else {
        if (idx + 0 < HL) c.x = hist[idx + 0];
        if (idx + 1 < HL) c.y = hist[idx + 1];
        if (idx + 2 < HL) c.z = hist[idx + 2];
        if (idx + 3 < HL) c.w = hist[idx + 3];
    }
    int s = c.x + c.y + c.z + c.w;

    int v = s;
    for (int off = 1; off < 64; off <<= 1) {
        int u = __shfl_up(v, off);
        if (lane >= off) v += u;
    }
    if (lane == 63) waveS[wave] = v;
    __syncthreads();
    int waveBase = 0;
    for (int w = 0; w < 4; ++w) if (w < wave) waveBase += waveS[w];
    int excl = bOff + waveBase + (v - s);

    int4 rs;
    rs.x = excl;
    rs.y = excl + c.x;
    rs.z = excl + c.x + c.y;
    rs.w = excl + c.x + c.y + c.z;
    if (idx + 3 < HL) {
        *(int4*)(histS + idx) = rs;
    } else {
        if (idx + 0 < HL) histS[idx + 0] = rs.x;
        if (idx + 1 < HL) histS[idx + 1] = rs.y;
        if (idx + 2 < HL) histS[idx + 2] = rs.z;
        if (idx + 3 < HL) histS[idx + 3] = rs.w;
    }
}

// ---- partition edges into bucket-contiguous tmp (LDS cursors) ----
// record: bits[8:0]=d&511, bits[28:9]=src, bits[63:32]=ew bits

__global__ __launch_bounds__(256) void k_partition(const int* __restrict__ src,
                                                   const int* __restrict__ dst,
                                                   const float* __restrict__ ew,
                                                   const int* __restrict__ histS,
                                                   unsigned long long* __restrict__ tmp) {
    __shared__ int base_[NB];
    const int t = threadIdx.x;
    if (t < NB) base_[t] = histS[t * NPB + blockIdx.x];
    __syncthreads();
    const int eb = blockIdx.x * EB;
#pragma unroll
    for (int i = 0; i < 8; ++i) {
        int e = eb + t + i * 256;
        if (e < E) {
            int d = __builtin_nontemporal_load(dst + e);
            int s = __builtin_nontemporal_load(src + e);
            float w = __builtin_nontemporal_load(ew + e);
            int b = d >> 9;
            int pos = atomicAdd(&base_[b], 1);
            unsigned long long rec =
                ((unsigned long long)(unsigned int)__float_as_int(w) << 32) |
                ((unsigned int)s << 9) | (unsigned int)(d & 511);
            __builtin_nontemporal_store(rec, tmp + pos);
        }
    }
}

// ---- per-bucket local sort; writes rowStart, dis, node-sorted pairs (src, raw ew) ----

__global__ __launch_bounds__(256) void k_local(const unsigned long long* __restrict__ tmp,
                                               const int* __restrict__ histS,
                                               float* __restrict__ dis,
                                               int* __restrict__ rowStart,
                                               int2* __restrict__ pairs) {
    const int b = blockIdx.x;
    const int t = threadIdx.x;
    const int segBeg = histS[b * NPB];
    const int segEnd = (b + 1 < NB) ? histS[(b + 1) * NPB] : E;

    __shared__ int   cnt[512];
    __shared__ float wsum[512];
    __shared__ int   off[512];
    __shared__ int   waveS[4];
    cnt[t] = 0; cnt[t + 256] = 0;
    wsum[t] = 0.f; wsum[t + 256] = 0.f;
    __syncthreads();

    for (int e = segBeg + t; e < segEnd; e += 256) {
        unsigned long long rec = tmp[e];
        int dl = (int)(rec & 511);
        float w = __uint_as_float((unsigned int)(rec >> 32));
        atomicAdd(&cnt[dl], 1);
        atomicAdd(&wsum[dl], w);
    }
    __syncthreads();

    const int i0 = t * 2, i1 = t * 2 + 1;
    const int c0 = cnt[i0], c1 = cnt[i1];
    const int pv = c0 + c1;
    const int lane = t & 63, wv = t >> 6;
    int v = pv;
    for (int o = 1; o < 64; o <<= 1) {
        int u = __shfl_up(v, o);
        if (lane >= o) v += u;
    }
    if (lane == 63) waveS[wv] = v;
    __syncthreads();
    int wb = 0;
    for (int w = 0; w < 4; ++w) if (w < wv) wb += waveS[w];
    const int ex = wb + v - pv;
    off[i0] = ex;
    off[i1] = ex + c0;
    const int node0 = b * 512 + i0, node1 = b * 512 + i1;
    if (node0 < N) { rowStart[node0] = segBeg + ex;      dis[node0] = rsqrtf(1.0f + wsum[i0]); }
    if (node1 < N) { rowStart[node1] = segBeg + ex + c0; dis[node1] = rsqrtf(1.0f + wsum[i1]); }
    cnt[i0] = 0; cnt[i1] = 0;
    if (b == NB - 1 && t == 0) rowStart[N] = E;
    __syncthreads();

    for (int e = segBeg + t; e < segEnd; e += 256) {
        unsigned long long rec = tmp[e];
        int dl = (int)(rec & 511);
        int s  = (int)((rec >> 9) & 0xFFFFF);
        unsigned int wbits = (unsigned int)(rec >> 32);
        int r = atomicAdd(&cnt[dl], 1);
        pairs[segBeg + off[dl] + r] = make_int2(s, (int)wbits);
    }
}

// ---------------- MFMA GEMM: 256 rows/block, 4 waves; wave = 64 rows x 128 cols ----------------

template <bool BF16IN>
__device__ __forceinline__ void gemm_mfma_body(const void* __restrict__ Xin,
                                               const unsigned int* __restrict__ Wt,
                                               unsigned short* __restrict__ out) {
    __shared__ unsigned int Ws[128 * 68];
    const int t = threadIdx.x;
#pragma unroll
    for (int i = 0; i < 8; ++i) {
        int f4 = t + i * 256;        // uint4 index, 2048 total
        int n = f4 >> 4;
        int k4 = f4 & 15;
        uint4 w = ((const uint4*)Wt)[f4];
        *(uint4*)(&Ws[n * 68 + k4 * 4]) = w;
    }
    __syncthreads();

    const int wv = t >> 6, lane = t & 63;
    const int q = lane >> 4, l15 = lane & 15;
    const int rowBase = blockIdx.x * 256 + wv * 64;

    f32x4 acc[4][8] = {};
#pragma unroll
    for (int kc = 0; kc < 4; ++kc) {
        bf16x8 af[4];
#pragma unroll
        for (int rt = 0; rt < 4; ++rt) {
            int row = rowBase + rt * 16 + l15;
            if (row > N - 1) row = N - 1;
            union { uint4 u; bf16x8 v; } cv;
            if (BF16IN) {
                cv.u = *(const uint4*)((const unsigned int*)Xin + (size_t)row * 64 + kc * 16 + q * 4);
            } else {
                const float* xr = (const float*)Xin + (size_t)row * D + kc * 32 + q * 8;
                float4 x0 = *(const float4*)xr;
                float4 x1 = *(const float4*)(xr + 4);
                cv.u.x = pack_bf16x2(x0.x, x0.y);
                cv.u.y = pack_bf16x2(x0.z, x0.w);
                cv.u.z = pack_bf16x2(x1.x, x1.y);
                cv.u.w = pack_bf16x2(x1.z, x1.w);
            }
            af[rt] = cv.v;
        }
#pragma unroll
        for (int ct = 0; ct < 8; ++ct) {
            union { uint4 u; bf16x8 v; } bv;
            bv.u = *(const uint4*)(&Ws[(ct * 16 + l15) * 68 + kc * 16 + q * 4]);
#pragma unroll
            for (int rt = 0; rt < 4; ++rt)
                acc[rt][ct] = __builtin_amdgcn_mfma_f32_16x16x32_bf16(af[rt], bv.v, acc[rt][ct], 0, 0, 0);
        }
    }

#pragma unroll
    for (int rt = 0; rt < 4; ++rt) {
#pragma unroll
        for (int ct = 0; ct < 8; ++ct) {
            int col = ct * 16 + l15;
#pragma unroll
            for (int r = 0; r < 4; ++r) {
                int row = rowBase + rt * 16 + q * 4 + r;
                if (row < N) out[(size_t)row * D + col] = bf16_rne(acc[rt][ct][r]);
            }
        }
    }
}

__global__ __launch_bounds__(256) void k_gemm1(const float* __restrict__ x,
                                               const unsigned int* __restrict__ Wt1,
                                               unsigned short* __restrict__ A) {
    gemm_mfma_body<false>(x, Wt1, A);
}

__global__ __launch_bounds__(256) void k_gemm2(const unsigned short* __restrict__ B,
                                               const unsigned int* __restrict__ Wt2,
                                               unsigned short* __restrict__ A2) {
    gemm_mfma_body<true>(B, Wt2, A2);
}

// ---------------- aggregate layer 1 (needed nodes only): B = relu(dis*sum + A/deg + b1) ----------------
// One wave per node; lane owns a col-pair. v = ew*dis[src] computed on the fly
// (pairs/dis loads are wave-uniform -> broadcast). 8 gathers in flight.

__global__ __launch_bounds__(256) void k_aggregate(const unsigned int* __restrict__ Hb,
                                                   const int2* __restrict__ pairs,
                                                   const int* __restrict__ rowStart,
                                                   const float* __restrict__ dis,
                                                   const unsigned int* __restrict__ needed,
                                                   const float* __restrict__ b,
                                                   unsigned int* __restrict__ outB) {
    int node = blockIdx.x * 4 + (threadIdx.x >> 6);
    if (node >= N) return;
    if (!((needed[node >> 5] >> (node & 31)) & 1u)) return;  // row never consumed downstream
    int lane = threadIdx.x & 63;
    int beg = rowStart[node], end = rowStart[node + 1];

    float ax = 0.f, ay = 0.f;
    int j = beg;
    for (; j + 7 < end; j += 8) {
        int2 p[8];
        float vv[8];
        unsigned int h[8];
#pragma unroll
        for (int i = 0; i < 8; ++i) p[i] = pairs[j + i];
#pragma unroll
        for (int i = 0; i < 8; ++i) { h[i] = Hb[(size_t)p[i].x * 64 + lane]; vv[i] = dis[p[i].x]; }
#pragma unroll
        for (int i = 0; i < 8; ++i) {
            float v = __int_as_float(p[i].y) * vv[i];
            ax += bf16_lo(h[i]) * v;
            ay += bf16_hi(h[i]) * v;
        }
    }
    for (; j + 3 < end; j += 4) {
        int2 p[4];
        float vv[4];
        unsigned int h[4];
#pragma unroll
        for (int i = 0; i < 4; ++i) p[i] = pairs[j + i];
#pragma unroll
        for (int i = 0; i < 4; ++i) { h[i] = Hb[(size_t)p[i].x * 64 + lane]; vv[i] = dis[p[i].x]; }
#pragma unroll
        for (int i = 0; i < 4; ++i) {
            float v = __int_as_float(p[i].y) * vv[i];
            ax += bf16_lo(h[i]) * v;
            ay += bf16_hi(h[i]) * v;
        }
    }
    for (; j < end; ++j) {
        int2 p0 = pairs[j];
        unsigned int h0 = Hb[(size_t)p0.x * 64 + lane];
        float v0 = __int_as_float(p0.y) * dis[p0.x];
        ax += bf16_lo(h0) * v0;
        ay += bf16_hi(h0) * v0;
    }

    float dd = dis[node];
    float sn = dd * dd;  // self-loop norm = 1/deg
    unsigned int hs = Hb[(size_t)node * 64 + lane];
    float2 bb = ((const float2*)b)[lane];
    float ox = fmaxf(ax * dd + bf16_lo(hs) * sn + bb.x, 0.f);
    float oy = fmaxf(ay * dd + bf16_hi(hs) * sn + bb.y, 0.f);
    __builtin_nontemporal_store(pack_bf16x2(ox, oy), outB + (size_t)node * 64 + lane);
}

// ---------------- layer-2 aggregate at mask nodes only -> d_out ----------------

__global__ __launch_bounds__(256) void k_aggregate_mask(const unsigned int* __restrict__ Hb,
                                                        const int2* __restrict__ pairs,
                                                        const int* __restrict__ rowStart,
                                                        const float* __restrict__ dis,
                                                        const float* __restrict__ b,
                                                        const int* __restrict__ mask,
                                                        const int* __restrict__ y,
                                                        float* __restrict__ out) {
    int i = blockIdx.x * 4 + (threadIdx.x >> 6);
    if (i >= M) return;
    int lane = threadIdx.x & 63;
    int node = mask[i];
    int beg = rowStart[node], end = rowStart[node + 1];

    float ax = 0.f, ay = 0.f;
    int j = beg;
    for (; j + 7 < end; j += 8) {
        int2 p[8];
        float vv[8];
        unsigned int h[8];
#pragma unroll
        for (int ii = 0; ii < 8; ++ii) p[ii] = pairs[j + ii];
#pragma unroll
        for (int ii = 0; ii < 8; ++ii) { h[ii] = Hb[(size_t)p[ii].x * 64 + lane]; vv[ii] = dis[p[ii].x]; }
#pragma unroll
        for (int ii = 0; ii < 8; ++ii) {
            float v = __int_as_float(p[ii].y) * vv[ii];
            ax += bf16_lo(h[ii]) * v;
            ay += bf16_hi(h[ii]) * v;
        }
    }
    for (; j < end; ++j) {
        int2 p0 = pairs[j];
        unsigned int h0 = Hb[(size_t)p0.x * 64 + lane];
        float v0 = __int_as_float(p0.y) * dis[p0.x];
        ax += bf16_lo(h0) * v0;
        ay += bf16_hi(h0) * v0;
    }

    float dd = dis[node];
    float sn = dd * dd;
    unsigned int hs = Hb[(size_t)node * 64 + lane];
    float2 bb = ((const float2*)b)[lane];
    float ox = ax * dd + bf16_lo(hs) * sn + bb.x;
    float oy = ay * dd + bf16_hi(hs) * sn + bb.y;
    ((float2*)(out + (size_t)i * D))[lane] = make_float2(ox, oy);
    if (lane == 0) out[(size_t)M * D + i] = (float)y[node];
}

extern "C" void kernel_launch(void* const* d_in, const int* in_sizes, int n_in,
                              void* d_out, int out_size, void* d_ws, size_t ws_size,
                              hipStream_t stream) {
    const float* x  = (const float*)d_in[0];
    const float* ew = (const float*)d_in[1];
    const float* W1 = (const float*)d_in[2];
    const float* b1 = (const float*)d_in[3];
    const float* W2 = (const float*)d_in[4];
    const float* b2 = (const float*)d_in[5];
    const int* eidx = (const int*)d_in[6];
    const int* mask = (const int*)d_in[7];
    const int* y    = (const int*)d_in[8];
    const int* src = eidx;       // edge_index[0]
    const int* dst = eidx + E;   // edge_index[1]

    // Workspace layout (bytes):
    //   dis       @ 0       : N f32       (0.4 MB)
    //   rowStart  @ 512 KB  : N+1 i32     (0.4 MB)
    //   scanBS    @ 1024 KB : SC_BLKS i32 (600 B)
    //   maskbit   @ 1056 KB : 16 KB bitmap  }  zeroed together (32 KB memset)
    //   needed    @ 1072 KB : 16 KB bitmap  }
    //   Wt1       @ 1088 KB : 8192 u32    (32 KB)
    //   Wt2       @ 1120 KB : 8192 u32    (32 KB)
    //   hist      @ 1280 KB : HL i32      (613 KB)
    //   histS     @ 1920 KB : HL i32      (613 KB)
    //   pairs     @ 3 MB    : E int2      (12.8 MB)
    //   A  (bf16) @ 16 MB   : N*D bf16    (25.6 MB)  [tmp (E u64) aliases A: dead
    //                                       before k_gemm1 writes A]
    //   B  (bf16) @ 42 MB   : N*D bf16    (25.6 MB)
    //   A2 (bf16) @ 68 MB   : N*D bf16    (25.6 MB)   total ~93.6 MB
    char* ws = (char*)d_ws;
    float* dis      = (float*)(ws);
    int*   rowStart = (int*)(ws + (size_t)512 * 1024);
    int*   scanBS   = (int*)(ws + (size_t)1024 * 1024);
    unsigned int* maskbit = (unsigned int*)(ws + (size_t)1056 * 1024);
    unsigned int* needed  = (unsigned int*)(ws + (size_t)1072 * 1024);
    unsigned int* Wt1 = (unsigned int*)(ws + (size_t)1088 * 1024);
    unsigned int* Wt2 = (unsigned int*)(ws + (size_t)1120 * 1024);
    int*   hist     = (int*)(ws + (size_t)1280 * 1024);
    int*   histS    = (int*)(ws + (size_t)1920 * 1024);
    int2*  pairs    = (int2*)(ws + (size_t)3 * 1024 * 1024);
    unsigned short* A  = (unsigned short*)(ws + (size_t)16 * 1024 * 1024);
    unsigned long long* tmp = (unsigned long long*)A;  // aliased; see lifetime note
    unsigned short* B  = (unsigned short*)(ws + (size_t)42 * 1024 * 1024);
    unsigned short* A2 = (unsigned short*)(ws + (size_t)68 * 1024 * 1024);

    // --- zero bitmaps, then fused hist + weight prep + maskbit ---
    (void)hipMemsetAsync(maskbit, 0, (size_t)32 * 1024, stream);
    hipLaunchKernelGGL(k_misc1, dim3(NPB + PREP_BLKS + MB_BLKS), dim3(256), 0, stream,
                       dst, hist, W1, Wt1, W2, Wt2, mask, maskbit, needed);

    // --- fused scan partials + needed-set edge scan ---
    hipLaunchKernelGGL(k_misc2, dim3(SC_BLKS + NPB), dim3(256), 0, stream,
                       hist, scanBS, maskbit, src, dst, needed);
    hipLaunchKernelGGL(k_scanf, dim3(SC_BLKS), dim3(256), 0, stream, hist, scanBS, histS);
    hipLaunchKernelGGL(k_partition, dim3(NPB), dim3(256), 0, stream, src, dst, ew, histS, tmp);
    hipLaunchKernelGGL(k_local, dim3(NB), dim3(256), 0, stream, tmp, histS, dis, rowStart, pairs);

    // --- layer 1: A = x@W1 (MFMA) ; B = relu(agg(A) + b1) at needed nodes only ---
    hipLaunchKernelGGL(k_gemm1, dim3(MF_BLKS), dim3(256), 0, stream, x, Wt1, A);
    hipLaunchKernelGGL(k_aggregate, dim3((N + 3) / 4), dim3(256), 0, stream,
                       (const unsigned int*)A, pairs, rowStart, dis, needed, b1,
                       (unsigned int*)B);

    // --- layer 2: A2 = B@W2 (MFMA) ; out = agg(A2) at mask nodes ---
    hipLaunchKernelGGL(k_gemm2, dim3(MF_BLKS), dim3(256), 0, stream, B, Wt2, A2);
    hipLaunchKernelGGL(k_aggregate_mask, dim3((M + 3) / 4), dim3(256), 0, stream,
                       (const unsigned int*)A2, pairs, rowStart, dis, b2, mask, y, (float*)d_out);
}

// Round 13
// 290.047 us; speedup vs baseline: 1.8741x; 1.0080x over previous
//
#include <hip/hip_runtime.h>

// Problem constants (fixed by the reference).
constexpr int N = 100000;   // nodes
constexpr int E = 1600000;  // edges
constexpr int D = 128;      // feature dim (both layers)
constexpr int M = 5000;     // mask size

constexpr int MF_BLKS = (N + 255) / 256;           // 391 mfma-gemm blocks (256 rows each)

// Counting-sort CSR build parameters.
constexpr int NB  = 196;                           // buckets: dst>>9, 512 nodes each
constexpr int EB  = 2048;                          // edges per hist/partition block
constexpr int NPB = (E + EB - 1) / EB;             // 782 partition blocks
constexpr int HL  = NB * NPB;                      // 153272 flat histogram entries
constexpr int SC_BLKS = (HL + 1023) / 1024;        // 150 scan blocks
constexpr int PREP_BLKS = 64;                      // weight-prep blocks (16384 threads)
constexpr int MB_BLKS = (M + 255) / 256;           // 20 maskbit blocks

typedef __attribute__((ext_vector_type(8))) short bf16x8;
typedef __attribute__((ext_vector_type(4))) float f32x4;

// ---------------- bf16 helpers (RNE pack, cheap unpack) ----------------

__device__ __forceinline__ unsigned int pack_bf16x2(float a, float b) {
    unsigned int ua = __float_as_uint(a);
    unsigned int ub = __float_as_uint(b);
    ua = (ua + 0x7FFFu + ((ua >> 16) & 1u)) >> 16;
    ub = (ub + 0x7FFFu + ((ub >> 16) & 1u)) & 0xFFFF0000u;
    return ua | ub;
}
__device__ __forceinline__ unsigned short bf16_rne(float a) {
    unsigned int ua = __float_as_uint(a);
    return (unsigned short)((ua + 0x7FFFu + ((ua >> 16) & 1u)) >> 16);
}
__device__ __forceinline__ float bf16_lo(unsigned int u) { return __uint_as_float(u << 16); }
__device__ __forceinline__ float bf16_hi(unsigned int u) { return __uint_as_float(u & 0xFFFF0000u); }

// ---------------- misc1: hist (LDS atomics) + weight prep + maskbit ----------------

__global__ __launch_bounds__(256) void k_misc1(const int* __restrict__ dst,
                                               int* __restrict__ hist,
                                               const float* __restrict__ W1,
                                               unsigned int* __restrict__ Wt1,
                                               const float* __restrict__ W2,
                                               unsigned int* __restrict__ Wt2,
                                               const int* __restrict__ mask,
                                               unsigned int* __restrict__ maskbit,
                                               unsigned int* __restrict__ needed) {
    __shared__ int h[NB];
    const int t = threadIdx.x;
    if (blockIdx.x < NPB) {
        if (t < NB) h[t] = 0;
        __syncthreads();
        const int base = blockIdx.x * EB;
#pragma unroll
        for (int i = 0; i < 8; ++i) {
            int e = base + t + i * 256;
            if (e < E) {
                int b = __builtin_nontemporal_load(dst + e) >> 9;
                atomicAdd(&h[b], 1);
            }
        }
        __syncthreads();
        if (t < NB) hist[t * NPB + blockIdx.x] = h[t];
    } else if (blockIdx.x < NPB + PREP_BLKS) {
        int gi = (blockIdx.x - NPB) * 256 + t;   // 16384 total
        const float* W = (gi < 8192) ? W1 : W2;
        unsigned int* Wt = (gi < 8192) ? Wt1 : Wt2;
        int idx = gi & 8191;
        int n = idx >> 6, kk = idx & 63;
        float a = W[(2 * kk) * D + n];
        float b = W[(2 * kk + 1) * D + n];
        Wt[idx] = pack_bf16x2(a, b);
    } else {
        int i = (blockIdx.x - NPB - PREP_BLKS) * 256 + t;
        if (i < M) {
            int n = mask[i];
            atomicOr(&maskbit[n >> 5], 1u << (n & 31));
            atomicOr(&needed[n >> 5], 1u << (n & 31));  // masked nodes need their own row
        }
    }
}

// ---------------- misc2: scan partials + needed-set edge scan ----------------

__global__ __launch_bounds__(256) void k_misc2(const int* __restrict__ hist,
                                               int* __restrict__ bs,
                                               const unsigned int* __restrict__ maskbit,
                                               const int* __restrict__ src,
                                               const int* __restrict__ dst,
                                               unsigned int* __restrict__ needed) {
    __shared__ int ws_[4];
    const int t = threadIdx.x;
    if (blockIdx.x < SC_BLKS) {
        const int idx = blockIdx.x * 1024 + t * 4;
        int s = 0;
        if (idx + 3 < HL) {
            int4 c = *(const int4*)(hist + idx);
            s = c.x + c.y + c.z + c.w;
        } else {
            for (int i = 0; i < 4; ++i) if (idx + i < HL) s += hist[idx + i];
        }
        for (int off = 32; off > 0; off >>= 1) s += __shfl_down(s, off);
        if ((t & 63) == 0) ws_[t >> 6] = s;
        __syncthreads();
        if (t == 0) bs[blockIdx.x] = ws_[0] + ws_[1] + ws_[2] + ws_[3];
    } else {
        const int base = (blockIdx.x - SC_BLKS) * EB;
#pragma unroll
        for (int i = 0; i < 8; ++i) {
            int e = base + t + i * 256;
            if (e < E) {
                int d = __builtin_nontemporal_load(dst + e);
                if ((maskbit[d >> 5] >> (d & 31)) & 1u) {
                    int s = src[e];
                    atomicOr(&needed[s >> 5], 1u << (s & 31));
                }
            }
        }
    }
}

// ---- scan final: each block inline-scans the 150 block sums, then its chunk ----

__global__ __launch_bounds__(256) void k_scanf(const int* __restrict__ hist,
                                               const int* __restrict__ bs,
                                               int* __restrict__ histS) {
    __shared__ int sh[256];
    __shared__ int waveS[4];
    const int t = threadIdx.x;
    const int lane = t & 63;
    const int wave = t >> 6;

    sh[t] = (t < SC_BLKS) ? bs[t] : 0;
    __syncthreads();
    for (int off = 1; off < 256; off <<= 1) {
        int u = (t >= off) ? sh[t - off] : 0;
        __syncthreads();
        sh[t] += u;
        __syncthreads();
    }
    const int bOff = sh[blockIdx.x] - bs[blockIdx.x];

    const int idx = blockIdx.x * 1024 + t * 4;
    int4 c = make_int4(0, 0, 0, 0);
    if (idx + 3 < HL) c = *(const int4*)(hist + idx);
    else {
        if (idx + 0 < HL) c.x = hist[idx + 0];
        if (idx + 1 < HL) c.y = hist[idx + 1];
        if (idx + 2 < HL) c.z = hist[idx + 2];
        if (idx + 3 < HL) c.w = hist[idx + 3];
    }
    int s = c.x + c.y + c.z + c.w;

    int v = s;
    for (int off = 1; off < 64; off <<= 1) {
        int u = __shfl_up(v, off);
        if (lane >= off) v += u;
    }
    if (lane == 63) waveS[wave] = v;
    __syncthreads();
    int waveBase = 0;
    for (int w = 0; w < 4; ++w) if (w < wave) waveBase += waveS[w];
    int excl = bOff + waveBase + (v - s);

    int4 rs;
    rs.x = excl;
    rs.y = excl + c.x;
    rs.z = excl + c.x + c.y;
    rs.w = excl + c.x + c.y + c.z;
    if (idx + 3 < HL) {
        *(int4*)(histS + idx) = rs;
    } else {
        if (idx + 0 < HL) histS[idx + 0] = rs.x;
        if (idx + 1 < HL) histS[idx + 1] = rs.y;
        if (idx + 2 < HL) histS[idx + 2] = rs.z;
        if (idx + 3 < HL) histS[idx + 3] = rs.w;
    }
}

// ---------------- MFMA GEMM body: 256 rows/block, 4 waves; wave = 64 rows x 128 cols ----------------
// A-frag: A[m=lane&15][k=quad*8+j]; B-frag: B[k=quad*8+j][n=lane&15];
// D: col=lane&15, row=quad*4+reg  (HW-verified layouts, 16x16x32 bf16).
// W^T staged in LDS with 68-uint row stride (bank-conflict padding).

template <bool BF16IN>
__device__ __forceinline__ void gemm_mfma_body(const void* __restrict__ Xin,
                                               const unsigned int* __restrict__ Wt,
                                               unsigned short* __restrict__ out, int blk) {
    __shared__ unsigned int Ws[128 * 68];
    const int t = threadIdx.x;
#pragma unroll
    for (int i = 0; i < 8; ++i) {
        int f4 = t + i * 256;        // uint4 index, 2048 total
        int n = f4 >> 4;
        int k4 = f4 & 15;
        uint4 w = ((const uint4*)Wt)[f4];
        *(uint4*)(&Ws[n * 68 + k4 * 4]) = w;
    }
    __syncthreads();

    const int wv = t >> 6, lane = t & 63;
    const int q = lane >> 4, l15 = lane & 15;
    const int rowBase = blk * 256 + wv * 64;

    f32x4 acc[4][8] = {};
#pragma unroll
    for (int kc = 0; kc < 4; ++kc) {
        bf16x8 af[4];
#pragma unroll
        for (int rt = 0; rt < 4; ++rt) {
            int row = rowBase + rt * 16 + l15;
            if (row > N - 1) row = N - 1;   // tail: duplicate last row, stores guarded
            union { uint4 u; bf16x8 v; } cv;
            if (BF16IN) {
                cv.u = *(const uint4*)((const unsigned int*)Xin + (size_t)row * 64 + kc * 16 + q * 4);
            } else {
                const float* xr = (const float*)Xin + (size_t)row * D + kc * 32 + q * 8;
                float4 x0 = *(const float4*)xr;
                float4 x1 = *(const float4*)(xr + 4);
                cv.u.x = pack_bf16x2(x0.x, x0.y);
                cv.u.y = pack_bf16x2(x0.z, x0.w);
                cv.u.z = pack_bf16x2(x1.x, x1.y);
                cv.u.w = pack_bf16x2(x1.z, x1.w);
            }
            af[rt] = cv.v;
        }
#pragma unroll
        for (int ct = 0; ct < 8; ++ct) {
            union { uint4 u; bf16x8 v; } bv;
            bv.u = *(const uint4*)(&Ws[(ct * 16 + l15) * 68 + kc * 16 + q * 4]);
#pragma unroll
            for (int rt = 0; rt < 4; ++rt)
                acc[rt][ct] = __builtin_amdgcn_mfma_f32_16x16x32_bf16(af[rt], bv.v, acc[rt][ct], 0, 0, 0);
        }
    }

#pragma unroll
    for (int rt = 0; rt < 4; ++rt) {
#pragma unroll
        for (int ct = 0; ct < 8; ++ct) {
            int col = ct * 16 + l15;
#pragma unroll
            for (int r = 0; r < 4; ++r) {
                int row = rowBase + rt * 16 + q * 4 + r;
                if (row < N) out[(size_t)row * D + col] = bf16_rne(acc[rt][ct][r]);
            }
        }
    }
}

// ---------------- fused: partition (LDS cursors) + GEMM1 (MFMA), range split ----------------
// Blocks [0,NPB): partition edges into bucket-contiguous tmp.
// Blocks [NPB, NPB+MF_BLKS): A = x@W1. Independent work; different pipes overlap.
// record: bits[8:0]=d&511, bits[28:9]=src, bits[63:32]=ew bits

__global__ __launch_bounds__(256) void k_part_g1(const int* __restrict__ src,
                                                 const int* __restrict__ dst,
                                                 const float* __restrict__ ew,
                                                 const int* __restrict__ histS,
                                                 unsigned long long* __restrict__ tmp,
                                                 const float* __restrict__ x,
                                                 const unsigned int* __restrict__ Wt1,
                                                 unsigned short* __restrict__ A) {
    if (blockIdx.x >= NPB) {
        gemm_mfma_body<false>(x, Wt1, A, blockIdx.x - NPB);
        return;
    }
    __shared__ int base_[NB];
    const int t = threadIdx.x;
    if (t < NB) base_[t] = histS[t * NPB + blockIdx.x];
    __syncthreads();
    const int eb = blockIdx.x * EB;
#pragma unroll
    for (int i = 0; i < 8; ++i) {
        int e = eb + t + i * 256;
        if (e < E) {
            int d = __builtin_nontemporal_load(dst + e);
            int s = __builtin_nontemporal_load(src + e);
            float w = __builtin_nontemporal_load(ew + e);
            int b = d >> 9;
            int pos = atomicAdd(&base_[b], 1);
            unsigned long long rec =
                ((unsigned long long)(unsigned int)__float_as_int(w) << 32) |
                ((unsigned int)s << 9) | (unsigned int)(d & 511);
            __builtin_nontemporal_store(rec, tmp + pos);
        }
    }
}

__global__ __launch_bounds__(256) void k_gemm2(const unsigned short* __restrict__ B,
                                               const unsigned int* __restrict__ Wt2,
                                               unsigned short* __restrict__ A2) {
    gemm_mfma_body<true>(B, Wt2, A2, blockIdx.x);
}

// ---- per-bucket local sort; writes rowStart, dis, node-sorted pairs (src, raw ew) ----

__global__ __launch_bounds__(256) void k_local(const unsigned long long* __restrict__ tmp,
                                               const int* __restrict__ histS,
                                               float* __restrict__ dis,
                                               int* __restrict__ rowStart,
                                               int2* __restrict__ pairs) {
    const int b = blockIdx.x;
    const int t = threadIdx.x;
    const int segBeg = histS[b * NPB];
    const int segEnd = (b + 1 < NB) ? histS[(b + 1) * NPB] : E;

    __shared__ int   cnt[512];
    __shared__ float wsum[512];
    __shared__ int   off[512];
    __shared__ int   waveS[4];
    cnt[t] = 0; cnt[t + 256] = 0;
    wsum[t] = 0.f; wsum[t + 256] = 0.f;
    __syncthreads();

    for (int e = segBeg + t; e < segEnd; e += 256) {
        unsigned long long rec = tmp[e];
        int dl = (int)(rec & 511);
        float w = __uint_as_float((unsigned int)(rec >> 32));
        atomicAdd(&cnt[dl], 1);
        atomicAdd(&wsum[dl], w);
    }
    __syncthreads();

    const int i0 = t * 2, i1 = t * 2 + 1;
    const int c0 = cnt[i0], c1 = cnt[i1];
    const int pv = c0 + c1;
    const int lane = t & 63, wv = t >> 6;
    int v = pv;
    for (int o = 1; o < 64; o <<= 1) {
        int u = __shfl_up(v, o);
        if (lane >= o) v += u;
    }
    if (lane == 63) waveS[wv] = v;
    __syncthreads();
    int wb = 0;
    for (int w = 0; w < 4; ++w) if (w < wv) wb += waveS[w];
    const int ex = wb + v - pv;
    off[i0] = ex;
    off[i1] = ex + c0;
    const int node0 = b * 512 + i0, node1 = b * 512 + i1;
    if (node0 < N) { rowStart[node0] = segBeg + ex;      dis[node0] = rsqrtf(1.0f + wsum[i0]); }
    if (node1 < N) { rowStart[node1] = segBeg + ex + c0; dis[node1] = rsqrtf(1.0f + wsum[i1]); }
    cnt[i0] = 0; cnt[i1] = 0;
    if (b == NB - 1 && t == 0) rowStart[N] = E;
    __syncthreads();

    for (int e = segBeg + t; e < segEnd; e += 256) {
        unsigned long long rec = tmp[e];
        int dl = (int)(rec & 511);
        int s  = (int)((rec >> 9) & 0xFFFFF);
        unsigned int wbits = (unsigned int)(rec >> 32);
        int r = atomicAdd(&cnt[dl], 1);
        pairs[segBeg + off[dl] + r] = make_int2(s, (int)wbits);
    }
}

// ---------------- aggregate layer 1 (needed nodes only): B = relu(dis*sum + A/deg + b1) ----------------
// One wave per node; lane owns a col-pair. v = ew*dis[src] computed on the fly
// (pairs/dis loads are wave-uniform -> broadcast). 8 gathers in flight.

__global__ __launch_bounds__(256) void k_aggregate(const unsigned int* __restrict__ Hb,
                                                   const int2* __restrict__ pairs,
                                                   const int* __restrict__ rowStart,
                                                   const float* __restrict__ dis,
                                                   const unsigned int* __restrict__ needed,
                                                   const float* __restrict__ b,
                                                   unsigned int* __restrict__ outB) {
    int node = blockIdx.x * 4 + (threadIdx.x >> 6);
    if (node >= N) return;
    if (!((needed[node >> 5] >> (node & 31)) & 1u)) return;  // row never consumed downstream
    int lane = threadIdx.x & 63;
    int beg = rowStart[node], end = rowStart[node + 1];

    float ax = 0.f, ay = 0.f;
    int j = beg;
    for (; j + 7 < end; j += 8) {
        int2 p[8];
        float vv[8];
        unsigned int h[8];
#pragma unroll
        for (int i = 0; i < 8; ++i) p[i] = pairs[j + i];
#pragma unroll
        for (int i = 0; i < 8; ++i) { h[i] = Hb[(size_t)p[i].x * 64 + lane]; vv[i] = dis[p[i].x]; }
#pragma unroll
        for (int i = 0; i < 8; ++i) {
            float v = __int_as_float(p[i].y) * vv[i];
            ax += bf16_lo(h[i]) * v;
            ay += bf16_hi(h[i]) * v;
        }
    }
    for (; j + 3 < end; j += 4) {
        int2 p[4];
        float vv[4];
        unsigned int h[4];
#pragma unroll
        for (int i = 0; i < 4; ++i) p[i] = pairs[j + i];
#pragma unroll
        for (int i = 0; i < 4; ++i) { h[i] = Hb[(size_t)p[i].x * 64 + lane]; vv[i] = dis[p[i].x]; }
#pragma unroll
        for (int i = 0; i < 4; ++i) {
            float v = __int_as_float(p[i].y) * vv[i];
            ax += bf16_lo(h[i]) * v;
            ay += bf16_hi(h[i]) * v;
        }
    }
    for (; j < end; ++j) {
        int2 p0 = pairs[j];
        unsigned int h0 = Hb[(size_t)p0.x * 64 + lane];
        float v0 = __int_as_float(p0.y) * dis[p0.x];
        ax += bf16_lo(h0) * v0;
        ay += bf16_hi(h0) * v0;
    }

    float dd = dis[node];
    float sn = dd * dd;  // self-loop norm = 1/deg
    unsigned int hs = Hb[(size_t)node * 64 + lane];
    float2 bb = ((const float2*)b)[lane];
    float ox = fmaxf(ax * dd + bf16_lo(hs) * sn + bb.x, 0.f);
    float oy = fmaxf(ay * dd + bf16_hi(hs) * sn + bb.y, 0.f);
    __builtin_nontemporal_store(pack_bf16x2(ox, oy), outB + (size_t)node * 64 + lane);
}

// ---------------- layer-2 aggregate at mask nodes only -> d_out ----------------

__global__ __launch_bounds__(256) void k_aggregate_mask(const unsigned int* __restrict__ Hb,
                                                        const int2* __restrict__ pairs,
                                                        const int* __restrict__ rowStart,
                                                        const float* __restrict__ dis,
                                                        const float* __restrict__ b,
                                                        const int* __restrict__ mask,
                                                        const int* __restrict__ y,
                                                        float* __restrict__ out) {
    int i = blockIdx.x * 4 + (threadIdx.x >> 6);
    if (i >= M) return;
    int lane = threadIdx.x & 63;
    int node = mask[i];
    int beg = rowStart[node], end = rowStart[node + 1];

    float ax = 0.f, ay = 0.f;
    int j = beg;
    for (; j + 7 < end; j += 8) {
        int2 p[8];
        float vv[8];
        unsigned int h[8];
#pragma unroll
        for (int ii = 0; ii < 8; ++ii) p[ii] = pairs[j + ii];
#pragma unroll
        for (int ii = 0; ii < 8; ++ii) { h[ii] = Hb[(size_t)p[ii].x * 64 + lane]; vv[ii] = dis[p[ii].x]; }
#pragma unroll
        for (int ii = 0; ii < 8; ++ii) {
            float v = __int_as_float(p[ii].y) * vv[ii];
            ax += bf16_lo(h[ii]) * v;
            ay += bf16_hi(h[ii]) * v;
        }
    }
    for (; j < end; ++j) {
        int2 p0 = pairs[j];
        unsigned int h0 = Hb[(size_t)p0.x * 64 + lane];
        float v0 = __int_as_float(p0.y) * dis[p0.x];
        ax += bf16_lo(h0) * v0;
        ay += bf16_hi(h0) * v0;
    }

    float dd = dis[node];
    float sn = dd * dd;
    unsigned int hs = Hb[(size_t)node * 64 + lane];
    float2 bb = ((const float2*)b)[lane];
    float ox = ax * dd + bf16_lo(hs) * sn + bb.x;
    float oy = ay * dd + bf16_hi(hs) * sn + bb.y;
    ((float2*)(out + (size_t)i * D))[lane] = make_float2(ox, oy);
    if (lane == 0) out[(size_t)M * D + i] = (float)y[node];
}

extern "C" void kernel_launch(void* const* d_in, const int* in_sizes, int n_in,
                              void* d_out, int out_size, void* d_ws, size_t ws_size,
                              hipStream_t stream) {
    const float* x  = (const float*)d_in[0];
    const float* ew = (const float*)d_in[1];
    const float* W1 = (const float*)d_in[2];
    const float* b1 = (const float*)d_in[3];
    const float* W2 = (const float*)d_in[4];
    const float* b2 = (const float*)d_in[5];
    const int* eidx = (const int*)d_in[6];
    const int* mask = (const int*)d_in[7];
    const int* y    = (const int*)d_in[8];
    const int* src = eidx;       // edge_index[0]
    const int* dst = eidx + E;   // edge_index[1]

    // Workspace layout (bytes):
    //   dis       @ 0       : N f32       (0.4 MB)
    //   rowStart  @ 512 KB  : N+1 i32     (0.4 MB)
    //   scanBS    @ 1024 KB : SC_BLKS i32
    //   maskbit   @ 1056 KB : 16 KB bitmap  }  zeroed together (32 KB memset)
    //   needed    @ 1072 KB : 16 KB bitmap  }
    //   Wt1       @ 1088 KB : 8192 u32    (32 KB)
    //   Wt2       @ 1120 KB : 8192 u32    (32 KB)
    //   hist      @ 1280 KB : HL i32      (613 KB)
    //   histS     @ 1920 KB : HL i32      (613 KB)
    //   pairs     @ 3 MB    : E int2      (12.8 MB)
    //   tmp       @ 16 MB   : E u64       (12.8 MB)  [NOT aliased with A: k_part_g1
    //                                       writes tmp and A concurrently]
    //   A  (bf16) @ 29 MB   : N*D bf16    (25.6 MB)
    //   B  (bf16) @ 55 MB   : N*D bf16    (25.6 MB)
    //   A2 (bf16) @ 81 MB   : N*D bf16    (25.6 MB)   total ~106.6 MB
    char* ws = (char*)d_ws;
    float* dis      = (float*)(ws);
    int*   rowStart = (int*)(ws + (size_t)512 * 1024);
    int*   scanBS   = (int*)(ws + (size_t)1024 * 1024);
    unsigned int* maskbit = (unsigned int*)(ws + (size_t)1056 * 1024);
    unsigned int* needed  = (unsigned int*)(ws + (size_t)1072 * 1024);
    unsigned int* Wt1 = (unsigned int*)(ws + (size_t)1088 * 1024);
    unsigned int* Wt2 = (unsigned int*)(ws + (size_t)1120 * 1024);
    int*   hist     = (int*)(ws + (size_t)1280 * 1024);
    int*   histS    = (int*)(ws + (size_t)1920 * 1024);
    int2*  pairs    = (int2*)(ws + (size_t)3 * 1024 * 1024);
    unsigned long long* tmp = (unsigned long long*)(ws + (size_t)16 * 1024 * 1024);
    unsigned short* A  = (unsigned short*)(ws + (size_t)29 * 1024 * 1024);
    unsigned short* B  = (unsigned short*)(ws + (size_t)55 * 1024 * 1024);
    unsigned short* A2 = (unsigned short*)(ws + (size_t)81 * 1024 * 1024);

    // --- zero bitmaps, then fused hist + weight prep + maskbit ---
    (void)hipMemsetAsync(maskbit, 0, (size_t)32 * 1024, stream);
    hipLaunchKernelGGL(k_misc1, dim3(NPB + PREP_BLKS + MB_BLKS), dim3(256), 0, stream,
                       dst, hist, W1, Wt1, W2, Wt2, mask, maskbit, needed);

    // --- fused scan partials + needed-set edge scan ---
    hipLaunchKernelGGL(k_misc2, dim3(SC_BLKS + NPB), dim3(256), 0, stream,
                       hist, scanBS, maskbit, src, dst, needed);
    hipLaunchKernelGGL(k_scanf, dim3(SC_BLKS), dim3(256), 0, stream, hist, scanBS, histS);

    // --- fused partition + GEMM1 (independent; overlap on different pipes) ---
    hipLaunchKernelGGL(k_part_g1, dim3(NPB + MF_BLKS), dim3(256), 0, stream,
                       src, dst, ew, histS, tmp, x, Wt1, A);
    hipLaunchKernelGGL(k_local, dim3(NB), dim3(256), 0, stream, tmp, histS, dis, rowStart, pairs);

    // --- layer 1 aggregate at needed nodes only: B = relu(agg(A) + b1) ---
    hipLaunchKernelGGL(k_aggregate, dim3((N + 3) / 4), dim3(256), 0, stream,
                       (const unsigned int*)A, pairs, rowStart, dis, needed, b1,
                       (unsigned int*)B);

    // --- layer 2: A2 = B@W2 (MFMA) ; out = agg(A2) at mask nodes ---
    hipLaunchKernelGGL(k_gemm2, dim3(MF_BLKS), dim3(256), 0, stream, B, Wt2, A2);
    hipLaunchKernelGGL(k_aggregate_mask, dim3((M + 3) / 4), dim3(256), 0, stream,
                       (const unsigned int*)A2, pairs, rowStart, dis, b2, mask, y, (float*)d_out);
}